// Round 12
// baseline (535.353 us; speedup 1.0000x reference)
//
#include <hip/hip_runtime.h>
#include <hip/hip_bf16.h>
#include <math.h>

#define BATCH 32768
#define UNITS 512
#define NF 1215      // number of freqs = 2L-1
#define KF 2432      // padded 2*NF
#define NOUT 608     // 512 + 96

typedef __bf16 bf16x8 __attribute__((ext_vector_type(8)));
typedef float f32x4 __attribute__((ext_vector_type(4)));
typedef short s16x4 __attribute__((ext_vector_type(4)));
typedef short s16x8 __attribute__((ext_vector_type(8)));

__device__ __forceinline__ unsigned short f2b(float f) {
  unsigned u = __builtin_bit_cast(unsigned, f);
  u += 0x7fffu + ((u >> 16) & 1u);
  return (unsigned short)(u >> 16);
}
__device__ __forceinline__ float b2f(unsigned short h) {
  unsigned u = ((unsigned)h) << 16;
  return __builtin_bit_cast(float, u);
}

#if __has_builtin(__builtin_amdgcn_exp2f)
__device__ __forceinline__ float fexp2(float x) { return __builtin_amdgcn_exp2f(x); }
#else
__device__ __forceinline__ float fexp2(float x) { return exp2f(x); }
#endif
#if __has_builtin(__builtin_amdgcn_logf)
__device__ __forceinline__ float flog2(float x) { return __builtin_amdgcn_logf(x); }
#else
__device__ __forceinline__ float flog2(float x) { return log2f(x); }
#endif
#if __has_builtin(__builtin_amdgcn_rcpf)
__device__ __forceinline__ float frcp(float x) { return __builtin_amdgcn_rcpf(x); }
#else
__device__ __forceinline__ float frcp(float x) { return 1.f / x; }
#endif

// async global->LDS, 16B per lane; LDS dest = wave-uniform base + lane*16
__device__ __forceinline__ void gload16(const unsigned short* g, unsigned short* l) {
  __builtin_amdgcn_global_load_lds(
      (const __attribute__((address_space(1))) void*)g,
      (__attribute__((address_space(3))) void*)l, 16, 0, 0);
}

// counted vmcnt wait (N = allowed outstanding VMEM ops), literal-templated
template <int N> __device__ __forceinline__ void wait_vm() {
  if constexpr (N == 0)      asm volatile("s_waitcnt vmcnt(0)" ::: "memory");
  else if constexpr (N == 8) asm volatile("s_waitcnt vmcnt(8)" ::: "memory");
  else                       asm volatile("s_waitcnt vmcnt(9)" ::: "memory");
}
__device__ __forceinline__ void barrier_raw() {
  asm volatile("" ::: "memory");
  __builtin_amdgcn_s_barrier();
  asm volatile("" ::: "memory");
}

// ---------- prep: split fp32 -> bf16 hi + bf16 lo (lo = round(v - hi)) ----------
__global__ __launch_bounds__(256) void split_k4(
    const float* __restrict__ src, unsigned short* __restrict__ hi,
    unsigned short* __restrict__ lo, int n4)
{
  int i = blockIdx.x * 256 + threadIdx.x;
  int stride = gridDim.x * 256;
  for (; i < n4; i += stride) {
    f32x4 v = ((const f32x4*)src)[i];
    s16x4 h, l;
#pragma unroll
    for (int j = 0; j < 4; ++j) {
      unsigned short hb = f2b(v[j]);
      h[j] = (short)hb;
      l[j] = (short)f2b(v[j] - b2f(hb));
    }
    ((s16x4*)hi)[i] = h;
    ((s16x4*)lo)[i] = l;
  }
}

// ---------- prep: st[n][k] = S[k][n] as bf16, padded to [640][2432] ----------
__global__ __launch_bounds__(256) void st_prep(
    const float* __restrict__ sb, const float* __restrict__ sf,
    unsigned short* __restrict__ st)
{
  __shared__ float tile[32][33];
  int k0 = blockIdx.x * 32, n0 = blockIdx.y * 32;
  int tx = threadIdx.x, ty = threadIdx.y;
#pragma unroll
  for (int yy = 0; yy < 32; yy += 8) {
    int k = k0 + ty + yy, n = n0 + tx;
    float v = 0.f;
    if (k < 2430) {
      if (n < 512) v = sb[(size_t)k * 512 + n];
      else if (n < NOUT) v = sf[(size_t)k * 96 + (n - 512)];
    }
    tile[ty + yy][tx] = v;
  }
  __syncthreads();
#pragma unroll
  for (int yy = 0; yy < 32; yy += 8) {
    int n = n0 + ty + yy, k = k0 + tx;
    st[(size_t)n * KF + k] = f2b(tile[tx][ty + yy]);
  }
}

// ---------- FC GEMM: C[M][512] = A[M][512] * W[512][512]^T, split-bf16 ----------
// 128x128 tile, 4 waves, NBUF=2. Per iter: STAGE(next tile, other buf) ->
// vmcnt(8) -> barrier -> compute -> barrier. NO setprio (round-9 lesson).
template <int NBN>
__global__ __launch_bounds__(256) void gemm_fc(
    const unsigned short* __restrict__ Agh, const unsigned short* __restrict__ Agl,
    const unsigned short* __restrict__ Bgh, const unsigned short* __restrict__ Bgl,
    const float* __restrict__ bias,
    unsigned short* __restrict__ Chi, unsigned short* __restrict__ Clo)
{
  constexpr int NT = 512 / 32;
  __shared__ unsigned short Ah[2][128 * 32];
  __shared__ unsigned short Bh[2][128 * 32];
  __shared__ unsigned short Al[2][128 * 32];
  __shared__ unsigned short Bl[2][128 * 32];

  const int t = threadIdx.x;
  const int lane = t & 63;
  const int w = t >> 6;
  const int wr = w >> 1, wc = w & 1;

  // XCD-aware mapping (BATCH/128 = 256 bm panels, 32 per XCD)
  const int lin = blockIdx.x;
  const int xcd = lin & 7;
  const int sub = lin >> 3;
  const long bm = (long)(xcd * 32 + sub / NBN) * 128;
  const int bn = (sub % NBN) * 128;

  const int lr = lane & 15, kg = lane >> 4;

  // staging: wave w fills windows w and w+4 (16 rows x 32 cols = 1KB each);
  // lane l -> row base+(l>>2), chunk l&3; inverse read-swizzle on global src.
  const int Rw = lane >> 2;
  const int pch = lane & 3;
  const int R1 = w * 16 + Rw;
  const int R2 = (w + 4) * 16 + Rw;
  const int s1 = (pch - (R1 >> 1)) & 3;
  const int s2 = (pch - (R2 >> 1)) & 3;
  const size_t oA1 = (size_t)(bm + R1) * UNITS + s1 * 8;
  const size_t oA2 = (size_t)(bm + R2) * UNITS + s2 * 8;
  const size_t oB1 = (size_t)(bn + R1) * UNITS + s1 * 8;
  const size_t oB2 = (size_t)(bn + R2) * UNITS + s2 * 8;

  auto STAGE = [&](int buf, int kt) {
    gload16(Agh + oA1 + kt, &Ah[buf][w * 512]);
    gload16(Agh + oA2 + kt, &Ah[buf][(w + 4) * 512]);
    gload16(Bgh + oB1 + kt, &Bh[buf][w * 512]);
    gload16(Bgh + oB2 + kt, &Bh[buf][(w + 4) * 512]);
    gload16(Agl + oA1 + kt, &Al[buf][w * 512]);
    gload16(Agl + oA2 + kt, &Al[buf][(w + 4) * 512]);
    gload16(Bgl + oB1 + kt, &Bl[buf][w * 512]);
    gload16(Bgl + oB2 + kt, &Bl[buf][(w + 4) * 512]);
  };

  const f32x4 fzero = {0.f, 0.f, 0.f, 0.f};
  f32x4 acc[4][4];
#pragma unroll
  for (int m = 0; m < 4; ++m)
#pragma unroll
    for (int n = 0; n < 4; ++n) acc[m][n] = fzero;

  STAGE(0, 0);
  int cur = 0;
  for (int it = 0; it < NT; ++it) {
    if (it + 1 < NT) { STAGE(cur ^ 1, (it + 1) * 32); wait_vm<8>(); }
    else wait_vm<0>();
    barrier_raw();  // stage(it) visible to all waves

    bf16x8 bhf[4], blf[4];
#pragma unroll
    for (int n = 0; n < 4; ++n) {
      int R = wc * 64 + n * 16 + lr;
      int phys = R * 32 + (((kg + (R >> 1)) & 3) << 3);
      bhf[n] = *(const bf16x8*)&Bh[cur][phys];
      blf[n] = *(const bf16x8*)&Bl[cur][phys];
    }
#pragma unroll
    for (int m = 0; m < 4; ++m) {
      int R = wr * 64 + m * 16 + lr;
      int phys = R * 32 + (((kg + (R >> 1)) & 3) << 3);
      bf16x8 ahf = *(const bf16x8*)&Ah[cur][phys];
      bf16x8 alf = *(const bf16x8*)&Al[cur][phys];
#pragma unroll
      for (int n = 0; n < 4; ++n) {
        acc[m][n] = __builtin_amdgcn_mfma_f32_16x16x32_bf16(ahf, bhf[n], acc[m][n], 0, 0, 0);
        acc[m][n] = __builtin_amdgcn_mfma_f32_16x16x32_bf16(ahf, blf[n], acc[m][n], 0, 0, 0);
        acc[m][n] = __builtin_amdgcn_mfma_f32_16x16x32_bf16(alf, bhf[n], acc[m][n], 0, 0, 0);
      }
    }
    barrier_raw();  // reads of buf `cur` done before next iter re-stages it
    cur ^= 1;
  }

  // epilogue: C/D layout col=lane&15, row=(lane>>4)*4+reg
#pragma unroll
  for (int m = 0; m < 4; ++m) {
#pragma unroll
    for (int n = 0; n < 4; ++n) {
      long gr0 = bm + wr * 64 + m * 16 + kg * 4;
      int gc = bn + wc * 64 + n * 16 + lr;
      float bv = bias[gc];
#pragma unroll
      for (int r = 0; r < 4; ++r) {
        float o = fmaxf(acc[m][n][r] + bv, 0.f);
        unsigned short h = f2b(o);
        size_t off = (size_t)(gr0 + r) * UNITS + gc;
        Chi[off] = h;
        Clo[off] = f2b(o - b2f(h));
      }
    }
  }
}

// ---------- final GEMM: out[M][608] = amps[M][KF] * st[640][KF]^T, plain bf16 ----
// WIDE tile: BM=128, BN=320, 4 waves, 40 MFMA/period.
// A-FRAGMENTS DIRECT FROM GLOBAL (L2): the MFMA A-operand is 16B/lane at
// A[bm+wr*64+m*16+lr][kt+kg*8], loadable as per-lane dwordx4 — removes the
// whole A LDS round-trip (stage-write + ds_read). Per-iter LDS traffic drops
// from (4A+10B read + 28KB write) to (10B read + 20KB write) per block.
// A prefetched 1 iter ahead into two NAMED register banks (rule #20: no
// runtime indexing), loop manually 2-unrolled. Only B uses LDS (40KB, dbuf).
// Per iter: STAGE_B(k+1)[5] -> LOAD_A(k+1)[4 plain loads] -> vmcnt(9)
// [B(k),A(k) landed; B(k+1)+A(k+1)=9 in flight] -> barrier -> MFMA -> barrier.
__global__ __launch_bounds__(256, 2) void gemm_wide(
    const unsigned short* __restrict__ Ag, const unsigned short* __restrict__ Bg,
    float* __restrict__ outF)
{
  constexpr int NT = KF / 32;  // 76
  __shared__ unsigned short Bh[2][320 * 32];   // 40KB

  const int t = threadIdx.x;
  const int lane = t & 63;
  const int w = t >> 6;
  const int wr = w >> 1, wc = w & 1;

  // XCD mapping: 256 bm panels x 2 bn tiles; 32 panels per XCD; the two bn
  // blocks of one panel land on the SAME XCD (amps panel L2-reuse).
  const int lin = blockIdx.x;
  const int xcd = lin & 7;
  const int sub = lin >> 3;           // 0..63
  const long bm = (long)(xcd * 32 + (sub >> 1)) * 128;
  const int bn = (sub & 1) * 320;

  const int lr = lane & 15, kg = lane >> 4;
  const int Rl = lane >> 2, pch = lane & 3;

  // B: 20 windows; wave w stages windows w*5 .. w*5+4 (inverse read-swizzle)
  size_t oB[5];
#pragma unroll
  for (int j = 0; j < 5; ++j) {
    int q = w * 5 + j;
    int R = q * 16 + Rl;
    int s = (pch - (R >> 1)) & 3;
    oB[j] = (size_t)(bn + R) * KF + s * 8;
  }
  auto STAGE_B = [&](int buf, int kt) {
#pragma unroll
    for (int j = 0; j < 5; ++j)
      gload16(Bg + oB[j] + kt, &Bh[buf][(w * 5 + j) * 512]);
  };

  // A fragment base: lane (lr,kg) reads A[bm+wr*64+m*16+lr][kt+kg*8 .. +8]
  const unsigned short* aPtr = Ag + (size_t)(bm + wr * 64 + lr) * KF + kg * 8;
  auto LOAD_A = [&](bf16x8 (&dst)[4], int kt) {
#pragma unroll
    for (int m = 0; m < 4; ++m)
      dst[m] = *(const bf16x8*)(aPtr + (size_t)m * 16 * KF + kt);
  };

  const f32x4 fzero = {0.f, 0.f, 0.f, 0.f};
  f32x4 acc[4][10];
#pragma unroll
  for (int m = 0; m < 4; ++m)
#pragma unroll
    for (int n = 0; n < 10; ++n) acc[m][n] = fzero;

  bf16x8 aA[4], aB[4];
  STAGE_B(0, 0);
  LOAD_A(aA, 0);

  int ib = 0;
  auto ITER = [&](bf16x8 (&acur)[4], bf16x8 (&anext)[4], int k) {
    if (k + 1 < NT) {
      STAGE_B(ib ^ 1, (k + 1) * 32);
      LOAD_A(anext, (k + 1) * 32);
      wait_vm<9>();
    } else {
      wait_vm<0>();
    }
    barrier_raw();  // B(k) in LDS for all waves; A(k) regs landed

#pragma unroll
    for (int n = 0; n < 10; ++n) {
      int R = wc * 160 + n * 16 + lr;
      bf16x8 bf = *(const bf16x8*)&Bh[ib][R * 32 + (((kg + (R >> 1)) & 3) << 3)];
#pragma unroll
      for (int m = 0; m < 4; ++m)
        acc[m][n] = __builtin_amdgcn_mfma_f32_16x16x32_bf16(acur[m], bf, acc[m][n], 0, 0, 0);
    }
    barrier_raw();  // reads of Bh[ib] done before it is re-staged
    ib ^= 1;
  };
  for (int k = 0; k < NT; k += 2) {  // NT even: two named A banks alternate
    ITER(aA, aB, k);
    ITER(aB, aA, k + 1);
  }

  // epilogue
#pragma unroll
  for (int m = 0; m < 4; ++m) {
#pragma unroll
    for (int n = 0; n < 10; ++n) {
      long gr0 = bm + wr * 64 + m * 16 + kg * 4;
      int gc = bn + wc * 160 + n * 16 + lr;
      if (gc < NOUT) {
#pragma unroll
        for (int r = 0; r < 4; ++r) {
          float o = acc[m][n][r];
          long row = gr0 + r;
          if (gc < 512) outF[row * 512 + gc] = o;
          else outF[(size_t)BATCH * 512 + row * 96 + (gc - 512)] = o;
        }
      }
    }
  }
}

// ---------- theta projection: coeff[M][32] = h3[M][512] * theta_w[32][512]^T, split-bf16 ----------
__global__ __launch_bounds__(256) void coeff_gemm(
    const unsigned short* __restrict__ Agh, const unsigned short* __restrict__ Agl,
    const unsigned short* __restrict__ Bgh, const unsigned short* __restrict__ Bgl,
    float* __restrict__ coeff)
{
  __shared__ unsigned short Ah[128 * 32];
  __shared__ unsigned short Al[128 * 32];
  __shared__ unsigned short Bh[32 * 32];
  __shared__ unsigned short Bl[32 * 32];

  const int t = threadIdx.x;
  const int lane = t & 63;
  const int w = t >> 6;
  const long bm = (long)blockIdx.x * 128;
  const int lr = lane & 15, kg = lane >> 4;

  const f32x4 fzero = {0.f, 0.f, 0.f, 0.f};
  f32x4 acc[2][2];
#pragma unroll
  for (int m = 0; m < 2; ++m)
#pragma unroll
    for (int n = 0; n < 2; ++n) acc[m][n] = fzero;

  for (int kt = 0; kt < 512; kt += 32) {
    __syncthreads();
#pragma unroll
    for (int p = 0; p < 2; ++p) {
      int c = t + 256 * p;
      int row = c >> 2, slot = c & 3;
      int phys = row * 32 + (((slot + (row >> 1)) & 3) << 3);
      size_t go = (size_t)(bm + row) * UNITS + kt + slot * 8;
      *(s16x8*)&Ah[phys] = *(const s16x8*)&Agh[go];
      *(s16x8*)&Al[phys] = *(const s16x8*)&Agl[go];
    }
    if (t < 128) {
      int row = t >> 2, slot = t & 3;
      int phys = row * 32 + (((slot + (row >> 1)) & 3) << 3);
      size_t go = (size_t)row * UNITS + kt + slot * 8;
      *(s16x8*)&Bh[phys] = *(const s16x8*)&Bgh[go];
      *(s16x8*)&Bl[phys] = *(const s16x8*)&Bgl[go];
    }
    __syncthreads();

    bf16x8 bh[2], bl[2];
#pragma unroll
    for (int n = 0; n < 2; ++n) {
      int R = n * 16 + lr;
      int phys = R * 32 + (((kg + (R >> 1)) & 3) << 3);
      bh[n] = *(const bf16x8*)&Bh[phys];
      bl[n] = *(const bf16x8*)&Bl[phys];
    }
#pragma unroll
    for (int m = 0; m < 2; ++m) {
      int R = w * 32 + m * 16 + lr;
      int phys = R * 32 + (((kg + (R >> 1)) & 3) << 3);
      bf16x8 ah = *(const bf16x8*)&Ah[phys];
      bf16x8 al = *(const bf16x8*)&Al[phys];
#pragma unroll
      for (int n = 0; n < 2; ++n) {
        acc[m][n] = __builtin_amdgcn_mfma_f32_16x16x32_bf16(ah, bh[n], acc[m][n], 0, 0, 0);
        acc[m][n] = __builtin_amdgcn_mfma_f32_16x16x32_bf16(ah, bl[n], acc[m][n], 0, 0, 0);
        acc[m][n] = __builtin_amdgcn_mfma_f32_16x16x32_bf16(al, bh[n], acc[m][n], 0, 0, 0);
      }
    }
  }
#pragma unroll
  for (int m = 0; m < 2; ++m)
#pragma unroll
    for (int n = 0; n < 2; ++n) {
      long gr0 = bm + w * 32 + m * 16 + kg * 4;
      int gc = n * 16 + lr;
#pragma unroll
      for (int r = 0; r < 4; ++r)
        coeff[(size_t)(gr0 + r) * 32 + gc] = acc[m][n][r];
    }
}

// ---------- gaussian head: one wave per batch row, 4 rows/block ----------
// SINGLE exp2 pass: e truncated to bf16, packed 2/u32 via v_perm (1 inst).
// sm accumulates untruncated e (bias ~2^-10 relative on amps, negligible).
// asm "+v" keeps packed words opaque (no remat of exp2 chain). Closed-form
// softmax max via endpoint convexity; hw trans pipe; base-2 softmax.
__global__ __launch_bounds__(256, 1) void gauss_kernel(
    const float* __restrict__ coeff, const float* __restrict__ fn_g,
    const float* __restrict__ fn_b, const float* __restrict__ wn_g,
    const float* __restrict__ wn_b, const float* __restrict__ freqs,
    unsigned short* __restrict__ amps)
{
  const int wid = threadIdx.x >> 6;
  const int t = threadIdx.x & 63;
  const int b = blockIdx.x * 4 + wid;
  const float cv = coeff[(size_t)b * 32 + (t & 31)];
  const float L2E = 1.4426950408889634f;

  float c2[8], c3[8];
  float m2 = 0.f, m3 = 0.f;
#pragma unroll
  for (int g = 0; g < 8; ++g) {
    c2[g] = __shfl(cv, 4 * g + 2);
    c3[g] = __shfl(cv, 4 * g + 3);
    m2 += c2[g]; m3 += c3[g];
  }
  m2 *= 0.125f; m3 *= 0.125f;
  float v2 = 0.f, v3 = 0.f;
#pragma unroll
  for (int g = 0; g < 8; ++g) {
    float d2 = c2[g] - m2; v2 += d2 * d2;
    float d3 = c3[g] - m3; v3 += d3 * d3;
  }
  v2 *= 0.125f; v3 *= 0.125f;
  const float r2 = rsqrtf(v2 + 1e-5f), r3 = rsqrtf(v3 + 1e-5f);

  const float S2 = 0.8493218f;  // sqrt(0.5 * log2(e))
  const float fv0 = freqs[0], fvL = freqs[NF - 1];
  float aa[8], oo[8], mxm[8];
#pragma unroll
  for (int g = 0; g < 8; ++g) {
    float z3 = (c3[g] - m3) * r3 * fn_g[g] + fn_b[g];
    float sig = frcp(1.f + fexp2(-z3 * L2E));
    float cfg = frcp(1.f + sig * 608.f);
    float z2 = (c2[g] - m2) * r2 * wn_g[g] + wn_b[g];
    float x = 10.f * z2;
    float enx = fexp2(-fabsf(x) * L2E);
    float sp = (fmaxf(x, 0.f) + 0.6931471805599453f * flog2(1.f + enx)) * 0.1f;
    float iwg = cfg * frcp(fmaxf(sp, 1e-6f));
    aa[g] = iwg * S2;
    oo[g] = cfg * iwg * S2;
    float d0 = fmaf(fv0, aa[g], -oo[g]);
    float dL = fmaf(fvL, aa[g], -oo[g]);
    mxm[g] = fmaxf(d0 * d0, dL * dL);
  }

  float sm[8];
#pragma unroll
  for (int g = 0; g < 8; ++g) sm[g] = 0.f;

  // ---- single exponent pass: compute e, pack hi16s via v_perm, accumulate ----
  unsigned pk[19][4];
#pragma unroll
  for (int i = 0; i < 19; ++i) {
    int f = t + 64 * i;
    float fv = freqs[min(f, NF - 1)];
#pragma unroll
    for (int j = 0; j < 4; ++j) {
      float d0 = fmaf(fv, aa[2 * j], -oo[2 * j]);
      float e0 = fexp2(fmaf(d0, d0, -mxm[2 * j]));
      float d1 = fmaf(fv, aa[2 * j + 1], -oo[2 * j + 1]);
      float e1 = fexp2(fmaf(d1, d1, -mxm[2 * j + 1]));
      if (i == 18 && t == 63) { e0 = 0.f; e1 = 0.f; }
      // pw = [e1.hi16 | e0.hi16] in one v_perm
      unsigned pw = __builtin_amdgcn_perm(__builtin_bit_cast(unsigned, e1),
                                          __builtin_bit_cast(unsigned, e0),
                                          0x07060302u);
      asm volatile("" : "+v"(pw));  // opaque: forbid remat of the exp2 chain
      pk[i][j] = pw;
      sm[2 * j]     += e0;
      sm[2 * j + 1] += e1;
    }
  }

  float wsn[8], wcn[8];
#pragma unroll
  for (int g = 0; g < 8; ++g) {
#pragma unroll
    for (int m = 32; m >= 1; m >>= 1) sm[g] += __shfl_xor(sm[g], m);
    float inv = frcp(sm[g]);
    wsn[g] = __shfl(cv, 4 * g + 0) * inv;
    wcn[g] = __shfl(cv, 4 * g + 1) * inv;
  }

  // ---- accumulate + store from packed e ----
  size_t base = (size_t)b * KF;
#pragma unroll
  for (int i = 0; i < 19; ++i) {
    float as = 0.f, ac = 0.f;
#pragma unroll
    for (int j = 0; j < 4; ++j) {
      unsigned pw = pk[i][j];
      float e0 = __builtin_bit_cast(float, pw << 16);
      float e1 = __builtin_bit_cast(float, pw & 0xFFFF0000u);
      as = fmaf(e0, wsn[2 * j], as);
      as = fmaf(e1, wsn[2 * j + 1], as);
      ac = fmaf(e0, wcn[2 * j], ac);
      ac = fmaf(e1, wcn[2 * j + 1], ac);
    }
    int f = t + 64 * i;
    if (f < NF) {
      amps[base + f] = f2b(as);
      amps[base + NF + f] = f2b(ac);
    }
  }
  if (t == 0) {
    amps[base + 2430] = 0;
    amps[base + 2431] = 0;
  }
}

extern "C" void kernel_launch(void* const* d_in, const int* in_sizes, int n_in,
                              void* d_out, int out_size, void* d_ws, size_t ws_size,
                              hipStream_t stream) {
  (void)in_sizes; (void)n_in; (void)out_size; (void)ws_size;
  const float* x = (const float*)d_in[0];
  const float* fcw[4] = {(const float*)d_in[1], (const float*)d_in[3],
                         (const float*)d_in[5], (const float*)d_in[7]};
  const float* fcb[4] = {(const float*)d_in[2], (const float*)d_in[4],
                         (const float*)d_in[6], (const float*)d_in[8]};
  const float* theta_w = (const float*)d_in[9];
  const float* fn_g = (const float*)d_in[10];
  const float* fn_b = (const float*)d_in[11];
  const float* wn_g = (const float*)d_in[12];
  const float* wn_b = (const float*)d_in[13];
  const float* freqs = (const float*)d_in[14];
  const float* sb = (const float*)d_in[15];
  const float* sf = (const float*)d_in[16];
  float* out = (float*)d_out;

  char* p = (char*)d_ws;
  auto take = [&](size_t bytes) {
    char* r = p;
    p += (bytes + 255) & ~(size_t)255;
    return r;
  };
  unsigned short* h0h = (unsigned short*)take((size_t)BATCH * UNITS * 2);
  unsigned short* h0l = (unsigned short*)take((size_t)BATCH * UNITS * 2);
  unsigned short* h1h = (unsigned short*)take((size_t)BATCH * UNITS * 2);
  unsigned short* h1l = (unsigned short*)take((size_t)BATCH * UNITS * 2);
  unsigned short *wh[4], *wl[4];
  for (int l = 0; l < 4; ++l) {
    wh[l] = (unsigned short*)take((size_t)UNITS * UNITS * 2);
    wl[l] = (unsigned short*)take((size_t)UNITS * UNITS * 2);
  }
  unsigned short* twh = (unsigned short*)take((size_t)32 * UNITS * 2);
  unsigned short* twl = (unsigned short*)take((size_t)32 * UNITS * 2);
  float* coeff = (float*)take((size_t)BATCH * 32 * 4);
  unsigned short* st = (unsigned short*)take((size_t)640 * KF * 2);
  unsigned short* amps = (unsigned short*)take((size_t)BATCH * KF * 2);

  // prep
  split_k4<<<2048, 256, 0, stream>>>(x, h0h, h0l, BATCH * UNITS / 4);
  for (int l = 0; l < 4; ++l)
    split_k4<<<256, 256, 0, stream>>>(fcw[l], wh[l], wl[l], UNITS * UNITS / 4);
  split_k4<<<16, 256, 0, stream>>>(theta_w, twh, twl, 32 * UNITS / 4);
  st_prep<<<dim3(KF / 32, 640 / 32), dim3(32, 8), 0, stream>>>(sb, sf, st);

  // FC stack (split-bf16): x->h1->h0->h1->h0   (1-D grid, XCD-aware mapping)
  gemm_fc<4><<<4 * (BATCH / 128), 256, 0, stream>>>(
      h0h, h0l, wh[0], wl[0], fcb[0], h1h, h1l);
  gemm_fc<4><<<4 * (BATCH / 128), 256, 0, stream>>>(
      h1h, h1l, wh[1], wl[1], fcb[1], h0h, h0l);
  gemm_fc<4><<<4 * (BATCH / 128), 256, 0, stream>>>(
      h0h, h0l, wh[2], wl[2], fcb[2], h1h, h1l);
  gemm_fc<4><<<4 * (BATCH / 128), 256, 0, stream>>>(
      h1h, h1l, wh[3], wl[3], fcb[3], h0h, h0l);

  // theta projection
  coeff_gemm<<<BATCH / 128, 256, 0, stream>>>(h0h, h0l, twh, twl, coeff);

  // gaussian head -> amps (bf16, padded to 2432)
  gauss_kernel<<<BATCH / 4, 256, 0, stream>>>(coeff, fn_g, fn_b, wn_g, wn_b, freqs, amps);

  // final GEMM -> backcast + forecast (wide tile: 128x320, 2 bn tiles)
  gemm_wide<<<2 * (BATCH / 128), 256, 0, stream>>>(amps, st, out);
}

// Round 13
// 521.222 us; speedup vs baseline: 1.0271x; 1.0271x over previous
//
#include <hip/hip_runtime.h>
#include <hip/hip_bf16.h>
#include <math.h>

#define BATCH 32768
#define UNITS 512
#define NF 1215      // number of freqs = 2L-1
#define KF 2432      // padded 2*NF
#define NOUT 608     // 512 + 96

typedef __bf16 bf16x8 __attribute__((ext_vector_type(8)));
typedef float f32x4 __attribute__((ext_vector_type(4)));
typedef short s16x4 __attribute__((ext_vector_type(4)));
typedef short s16x8 __attribute__((ext_vector_type(8)));

__device__ __forceinline__ unsigned short f2b(float f) {
  unsigned u = __builtin_bit_cast(unsigned, f);
  u += 0x7fffu + ((u >> 16) & 1u);
  return (unsigned short)(u >> 16);
}
__device__ __forceinline__ float b2f(unsigned short h) {
  unsigned u = ((unsigned)h) << 16;
  return __builtin_bit_cast(float, u);
}

#if __has_builtin(__builtin_amdgcn_exp2f)
__device__ __forceinline__ float fexp2(float x) { return __builtin_amdgcn_exp2f(x); }
#else
__device__ __forceinline__ float fexp2(float x) { return exp2f(x); }
#endif
#if __has_builtin(__builtin_amdgcn_logf)
__device__ __forceinline__ float flog2(float x) { return __builtin_amdgcn_logf(x); }
#else
__device__ __forceinline__ float flog2(float x) { return log2f(x); }
#endif
#if __has_builtin(__builtin_amdgcn_rcpf)
__device__ __forceinline__ float frcp(float x) { return __builtin_amdgcn_rcpf(x); }
#else
__device__ __forceinline__ float frcp(float x) { return 1.f / x; }
#endif

// async global->LDS, 16B per lane; LDS dest = wave-uniform base + lane*16
__device__ __forceinline__ void gload16(const unsigned short* g, unsigned short* l) {
  __builtin_amdgcn_global_load_lds(
      (const __attribute__((address_space(1))) void*)g,
      (__attribute__((address_space(3))) void*)l, 16, 0, 0);
}

// counted vmcnt wait (N = allowed outstanding VMEM ops), literal-templated
template <int N> __device__ __forceinline__ void wait_vm() {
  if constexpr (N == 0)      asm volatile("s_waitcnt vmcnt(0)" ::: "memory");
  else if constexpr (N == 7) asm volatile("s_waitcnt vmcnt(7)" ::: "memory");
  else                       asm volatile("s_waitcnt vmcnt(8)" ::: "memory");
}
__device__ __forceinline__ void barrier_raw() {
  asm volatile("" ::: "memory");
  __builtin_amdgcn_s_barrier();
  asm volatile("" ::: "memory");
}

// ---------- prep: split fp32 -> bf16 hi + bf16 lo (lo = round(v - hi)) ----------
__global__ __launch_bounds__(256) void split_k4(
    const float* __restrict__ src, unsigned short* __restrict__ hi,
    unsigned short* __restrict__ lo, int n4)
{
  int i = blockIdx.x * 256 + threadIdx.x;
  int stride = gridDim.x * 256;
  for (; i < n4; i += stride) {
    f32x4 v = ((const f32x4*)src)[i];
    s16x4 h, l;
#pragma unroll
    for (int j = 0; j < 4; ++j) {
      unsigned short hb = f2b(v[j]);
      h[j] = (short)hb;
      l[j] = (short)f2b(v[j] - b2f(hb));
    }
    ((s16x4*)hi)[i] = h;
    ((s16x4*)lo)[i] = l;
  }
}

// ---------- prep: st[n][k] = S[k][n] as bf16, padded to [640][2432] ----------
__global__ __launch_bounds__(256) void st_prep(
    const float* __restrict__ sb, const float* __restrict__ sf,
    unsigned short* __restrict__ st)
{
  __shared__ float tile[32][33];
  int k0 = blockIdx.x * 32, n0 = blockIdx.y * 32;
  int tx = threadIdx.x, ty = threadIdx.y;
#pragma unroll
  for (int yy = 0; yy < 32; yy += 8) {
    int k = k0 + ty + yy, n = n0 + tx;
    float v = 0.f;
    if (k < 2430) {
      if (n < 512) v = sb[(size_t)k * 512 + n];
      else if (n < NOUT) v = sf[(size_t)k * 96 + (n - 512)];
    }
    tile[ty + yy][tx] = v;
  }
  __syncthreads();
#pragma unroll
  for (int yy = 0; yy < 32; yy += 8) {
    int n = n0 + ty + yy, k = k0 + tx;
    st[(size_t)n * KF + k] = f2b(tile[tx][ty + yy]);
  }
}

// ---------- FC GEMM: C[M][512] = A[M][512] * W[512][512]^T, split-bf16 ----------
// 128x128 tile, 4 waves, NBUF=2. Per iter: STAGE(next tile, other buf) ->
// vmcnt(8) -> barrier -> compute -> barrier. NO setprio (round-9 lesson).
template <int NBN>
__global__ __launch_bounds__(256) void gemm_fc(
    const unsigned short* __restrict__ Agh, const unsigned short* __restrict__ Agl,
    const unsigned short* __restrict__ Bgh, const unsigned short* __restrict__ Bgl,
    const float* __restrict__ bias,
    unsigned short* __restrict__ Chi, unsigned short* __restrict__ Clo)
{
  constexpr int NT = 512 / 32;
  __shared__ unsigned short Ah[2][128 * 32];
  __shared__ unsigned short Bh[2][128 * 32];
  __shared__ unsigned short Al[2][128 * 32];
  __shared__ unsigned short Bl[2][128 * 32];

  const int t = threadIdx.x;
  const int lane = t & 63;
  const int w = t >> 6;
  const int wr = w >> 1, wc = w & 1;

  // XCD-aware mapping (BATCH/128 = 256 bm panels, 32 per XCD)
  const int lin = blockIdx.x;
  const int xcd = lin & 7;
  const int sub = lin >> 3;
  const long bm = (long)(xcd * 32 + sub / NBN) * 128;
  const int bn = (sub % NBN) * 128;

  const int lr = lane & 15, kg = lane >> 4;

  // staging: wave w fills windows w and w+4 (16 rows x 32 cols = 1KB each);
  // lane l -> row base+(l>>2), chunk l&3; inverse read-swizzle on global src.
  const int Rw = lane >> 2;
  const int pch = lane & 3;
  const int R1 = w * 16 + Rw;
  const int R2 = (w + 4) * 16 + Rw;
  const int s1 = (pch - (R1 >> 1)) & 3;
  const int s2 = (pch - (R2 >> 1)) & 3;
  const size_t oA1 = (size_t)(bm + R1) * UNITS + s1 * 8;
  const size_t oA2 = (size_t)(bm + R2) * UNITS + s2 * 8;
  const size_t oB1 = (size_t)(bn + R1) * UNITS + s1 * 8;
  const size_t oB2 = (size_t)(bn + R2) * UNITS + s2 * 8;

  auto STAGE = [&](int buf, int kt) {
    gload16(Agh + oA1 + kt, &Ah[buf][w * 512]);
    gload16(Agh + oA2 + kt, &Ah[buf][(w + 4) * 512]);
    gload16(Bgh + oB1 + kt, &Bh[buf][w * 512]);
    gload16(Bgh + oB2 + kt, &Bh[buf][(w + 4) * 512]);
    gload16(Agl + oA1 + kt, &Al[buf][w * 512]);
    gload16(Agl + oA2 + kt, &Al[buf][(w + 4) * 512]);
    gload16(Bgl + oB1 + kt, &Bl[buf][w * 512]);
    gload16(Bgl + oB2 + kt, &Bl[buf][(w + 4) * 512]);
  };

  const f32x4 fzero = {0.f, 0.f, 0.f, 0.f};
  f32x4 acc[4][4];
#pragma unroll
  for (int m = 0; m < 4; ++m)
#pragma unroll
    for (int n = 0; n < 4; ++n) acc[m][n] = fzero;

  STAGE(0, 0);
  int cur = 0;
  for (int it = 0; it < NT; ++it) {
    if (it + 1 < NT) { STAGE(cur ^ 1, (it + 1) * 32); wait_vm<8>(); }
    else wait_vm<0>();
    barrier_raw();  // stage(it) visible to all waves

    bf16x8 bhf[4], blf[4];
#pragma unroll
    for (int n = 0; n < 4; ++n) {
      int R = wc * 64 + n * 16 + lr;
      int phys = R * 32 + (((kg + (R >> 1)) & 3) << 3);
      bhf[n] = *(const bf16x8*)&Bh[cur][phys];
      blf[n] = *(const bf16x8*)&Bl[cur][phys];
    }
#pragma unroll
    for (int m = 0; m < 4; ++m) {
      int R = wr * 64 + m * 16 + lr;
      int phys = R * 32 + (((kg + (R >> 1)) & 3) << 3);
      bf16x8 ahf = *(const bf16x8*)&Ah[cur][phys];
      bf16x8 alf = *(const bf16x8*)&Al[cur][phys];
#pragma unroll
      for (int n = 0; n < 4; ++n) {
        acc[m][n] = __builtin_amdgcn_mfma_f32_16x16x32_bf16(ahf, bhf[n], acc[m][n], 0, 0, 0);
        acc[m][n] = __builtin_amdgcn_mfma_f32_16x16x32_bf16(ahf, blf[n], acc[m][n], 0, 0, 0);
        acc[m][n] = __builtin_amdgcn_mfma_f32_16x16x32_bf16(alf, bhf[n], acc[m][n], 0, 0, 0);
      }
    }
    barrier_raw();  // reads of buf `cur` done before next iter re-stages it
    cur ^= 1;
  }

  // epilogue: C/D layout col=lane&15, row=(lane>>4)*4+reg
#pragma unroll
  for (int m = 0; m < 4; ++m) {
#pragma unroll
    for (int n = 0; n < 4; ++n) {
      long gr0 = bm + wr * 64 + m * 16 + kg * 4;
      int gc = bn + wc * 64 + n * 16 + lr;
      float bv = bias[gc];
#pragma unroll
      for (int r = 0; r < 4; ++r) {
        float o = fmaxf(acc[m][n][r] + bv, 0.f);
        unsigned short h = f2b(o);
        size_t off = (size_t)(gr0 + r) * UNITS + gc;
        Chi[off] = h;
        Clo[off] = f2b(o - b2f(h));
      }
    }
  }
}

// ---------- final GEMM: out[M][608] = amps[M][KF] * st[640][KF]^T, plain bf16 ----
// WIDE tile: BM=128, BN=320, 4 waves, wave = 64x160, 40 MFMA/period.
// Uniform NBUF=2 staged A+B (round-10 best: 125us; round-11 split-depth and
// round-12 A-direct-from-global both falsified). LDS 56KB -> 2 blocks/CU;
// grid = 512 = exactly 2/CU. launch_bounds(256,2) pins regalloc.
__global__ __launch_bounds__(256, 2) void gemm_wide(
    const unsigned short* __restrict__ Ag, const unsigned short* __restrict__ Bg,
    float* __restrict__ outF)
{
  constexpr int NT = KF / 32;  // 76
  __shared__ unsigned short Ah[2][128 * 32];
  __shared__ unsigned short Bh[2][320 * 32];

  const int t = threadIdx.x;
  const int lane = t & 63;
  const int w = t >> 6;
  const int wr = w >> 1, wc = w & 1;

  // XCD mapping: 256 bm panels x 2 bn tiles; 32 panels per XCD
  const int lin = blockIdx.x;
  const int xcd = lin & 7;
  const int sub = lin >> 3;           // 0..63
  const long bm = (long)(xcd * 32 + (sub >> 1)) * 128;
  const int bn = (sub & 1) * 320;

  const int lr = lane & 15, kg = lane >> 4;
  const int Rl = lane >> 2, pch = lane & 3;

  // A: 8 windows; wave w stages windows w, w+4
  const int RA1 = w * 16 + Rl, RA2 = (w + 4) * 16 + Rl;
  const int sA1 = (pch - (RA1 >> 1)) & 3, sA2 = (pch - (RA2 >> 1)) & 3;
  const size_t oA1 = (size_t)(bm + RA1) * KF + sA1 * 8;
  const size_t oA2 = (size_t)(bm + RA2) * KF + sA2 * 8;
  // B: 20 windows; wave w stages windows w*5 .. w*5+4
  size_t oB[5];
#pragma unroll
  for (int j = 0; j < 5; ++j) {
    int q = w * 5 + j;
    int R = q * 16 + Rl;
    int s = (pch - (R >> 1)) & 3;
    oB[j] = (size_t)(bn + R) * KF + s * 8;
  }

  auto STAGE = [&](int buf, int kt) {
    gload16(Ag + oA1 + kt, &Ah[buf][w * 512]);
    gload16(Ag + oA2 + kt, &Ah[buf][(w + 4) * 512]);
#pragma unroll
    for (int j = 0; j < 5; ++j)
      gload16(Bg + oB[j] + kt, &Bh[buf][(w * 5 + j) * 512]);
  };

  const f32x4 fzero = {0.f, 0.f, 0.f, 0.f};
  f32x4 acc[4][10];
#pragma unroll
  for (int m = 0; m < 4; ++m)
#pragma unroll
    for (int n = 0; n < 10; ++n) acc[m][n] = fzero;

  STAGE(0, 0);
  int cur = 0;
  for (int it = 0; it < NT; ++it) {
    if (it + 1 < NT) { STAGE(cur ^ 1, (it + 1) * 32); wait_vm<7>(); }
    else wait_vm<0>();
    barrier_raw();

    bf16x8 af[4];
#pragma unroll
    for (int m = 0; m < 4; ++m) {
      int R = wr * 64 + m * 16 + lr;
      af[m] = *(const bf16x8*)&Ah[cur][R * 32 + (((kg + (R >> 1)) & 3) << 3)];
    }
#pragma unroll
    for (int n = 0; n < 10; ++n) {
      int R = wc * 160 + n * 16 + lr;
      bf16x8 bf = *(const bf16x8*)&Bh[cur][R * 32 + (((kg + (R >> 1)) & 3) << 3)];
#pragma unroll
      for (int m = 0; m < 4; ++m)
        acc[m][n] = __builtin_amdgcn_mfma_f32_16x16x32_bf16(af[m], bf, acc[m][n], 0, 0, 0);
    }
    barrier_raw();
    cur ^= 1;
  }

  // epilogue
#pragma unroll
  for (int m = 0; m < 4; ++m) {
#pragma unroll
    for (int n = 0; n < 10; ++n) {
      long gr0 = bm + wr * 64 + m * 16 + kg * 4;
      int gc = bn + wc * 160 + n * 16 + lr;
      if (gc < NOUT) {
#pragma unroll
        for (int r = 0; r < 4; ++r) {
          float o = acc[m][n][r];
          long row = gr0 + r;
          if (gc < 512) outF[row * 512 + gc] = o;
          else outF[(size_t)BATCH * 512 + row * 96 + (gc - 512)] = o;
        }
      }
    }
  }
}

// ---------- theta projection: coeff[M][32] = h3[M][512] * theta_w[32][512]^T, split-bf16 ----------
__global__ __launch_bounds__(256) void coeff_gemm(
    const unsigned short* __restrict__ Agh, const unsigned short* __restrict__ Agl,
    const unsigned short* __restrict__ Bgh, const unsigned short* __restrict__ Bgl,
    float* __restrict__ coeff)
{
  __shared__ unsigned short Ah[128 * 32];
  __shared__ unsigned short Al[128 * 32];
  __shared__ unsigned short Bh[32 * 32];
  __shared__ unsigned short Bl[32 * 32];

  const int t = threadIdx.x;
  const int lane = t & 63;
  const int w = t >> 6;
  const long bm = (long)blockIdx.x * 128;
  const int lr = lane & 15, kg = lane >> 4;

  const f32x4 fzero = {0.f, 0.f, 0.f, 0.f};
  f32x4 acc[2][2];
#pragma unroll
  for (int m = 0; m < 2; ++m)
#pragma unroll
    for (int n = 0; n < 2; ++n) acc[m][n] = fzero;

  for (int kt = 0; kt < 512; kt += 32) {
    __syncthreads();
#pragma unroll
    for (int p = 0; p < 2; ++p) {
      int c = t + 256 * p;
      int row = c >> 2, slot = c & 3;
      int phys = row * 32 + (((slot + (row >> 1)) & 3) << 3);
      size_t go = (size_t)(bm + row) * UNITS + kt + slot * 8;
      *(s16x8*)&Ah[phys] = *(const s16x8*)&Agh[go];
      *(s16x8*)&Al[phys] = *(const s16x8*)&Agl[go];
    }
    if (t < 128) {
      int row = t >> 2, slot = t & 3;
      int phys = row * 32 + (((slot + (row >> 1)) & 3) << 3);
      size_t go = (size_t)row * UNITS + kt + slot * 8;
      *(s16x8*)&Bh[phys] = *(const s16x8*)&Bgh[go];
      *(s16x8*)&Bl[phys] = *(const s16x8*)&Bgl[go];
    }
    __syncthreads();

    bf16x8 bh[2], bl[2];
#pragma unroll
    for (int n = 0; n < 2; ++n) {
      int R = n * 16 + lr;
      int phys = R * 32 + (((kg + (R >> 1)) & 3) << 3);
      bh[n] = *(const bf16x8*)&Bh[phys];
      bl[n] = *(const bf16x8*)&Bl[phys];
    }
#pragma unroll
    for (int m = 0; m < 2; ++m) {
      int R = w * 32 + m * 16 + lr;
      int phys = R * 32 + (((kg + (R >> 1)) & 3) << 3);
      bf16x8 ah = *(const bf16x8*)&Ah[phys];
      bf16x8 al = *(const bf16x8*)&Al[phys];
#pragma unroll
      for (int n = 0; n < 2; ++n) {
        acc[m][n] = __builtin_amdgcn_mfma_f32_16x16x32_bf16(ah, bh[n], acc[m][n], 0, 0, 0);
        acc[m][n] = __builtin_amdgcn_mfma_f32_16x16x32_bf16(ah, bl[n], acc[m][n], 0, 0, 0);
        acc[m][n] = __builtin_amdgcn_mfma_f32_16x16x32_bf16(al, bh[n], acc[m][n], 0, 0, 0);
      }
    }
  }
#pragma unroll
  for (int m = 0; m < 2; ++m)
#pragma unroll
    for (int n = 0; n < 2; ++n) {
      long gr0 = bm + w * 32 + m * 16 + kg * 4;
      int gc = n * 16 + lr;
#pragma unroll
      for (int r = 0; r < 4; ++r)
        coeff[(size_t)(gr0 + r) * 32 + gc] = acc[m][n][r];
    }
}

// ---------- gaussian head: TWO waves per batch row (2 rows / 256-thr block) ----
// Wave `half` handles slot-groups g2 = 2i+half (i<10; g2=19 is fully padded),
// halving per-wave exp2/fma work. Per-wave partial denominators reduced by
// shfl, then combined across the wave pair via a 128B LDS patch + 1 barrier.
// Single exp2 pass: e truncated to bf16, packed 2/u32; sm accumulated from
// the SAME truncated values (consistent renorm, round-10 absmax). asm "+v"
// forbids remat of the exp2 chain. Closed-form softmax max via endpoint
// convexity; hw trans pipe; base-2: exp(0.5*d^2)==2^((d*s)^2).
__global__ __launch_bounds__(256, 1) void gauss_kernel(
    const float* __restrict__ coeff, const float* __restrict__ fn_g,
    const float* __restrict__ fn_b, const float* __restrict__ wn_g,
    const float* __restrict__ wn_b, const float* __restrict__ freqs,
    unsigned short* __restrict__ amps)
{
  const int wid = threadIdx.x >> 6;     // 0..3
  const int t = threadIdx.x & 63;
  const int rowb = wid >> 1;            // 0..1 : row within block
  const int half = wid & 1;             // 0..1 : slot-group parity
  const int b = blockIdx.x * 2 + rowb;
  __shared__ float smx[2][2][8];

  const float cv = coeff[(size_t)b * 32 + (t & 31)];
  const float L2E = 1.4426950408889634f;

  float c2[8], c3[8];
  float m2 = 0.f, m3 = 0.f;
#pragma unroll
  for (int g = 0; g < 8; ++g) {
    c2[g] = __shfl(cv, 4 * g + 2);
    c3[g] = __shfl(cv, 4 * g + 3);
    m2 += c2[g]; m3 += c3[g];
  }
  m2 *= 0.125f; m3 *= 0.125f;
  float v2 = 0.f, v3 = 0.f;
#pragma unroll
  for (int g = 0; g < 8; ++g) {
    float d2 = c2[g] - m2; v2 += d2 * d2;
    float d3 = c3[g] - m3; v3 += d3 * d3;
  }
  v2 *= 0.125f; v3 *= 0.125f;
  const float r2 = rsqrtf(v2 + 1e-5f), r3 = rsqrtf(v3 + 1e-5f);

  const float S2 = 0.8493218f;  // sqrt(0.5 * log2(e))
  const float fv0 = freqs[0], fvL = freqs[NF - 1];
  float aa[8], oo[8], mxm[8];
#pragma unroll
  for (int g = 0; g < 8; ++g) {
    float z3 = (c3[g] - m3) * r3 * fn_g[g] + fn_b[g];
    float sig = frcp(1.f + fexp2(-z3 * L2E));
    float cfg = frcp(1.f + sig * 608.f);
    float z2 = (c2[g] - m2) * r2 * wn_g[g] + wn_b[g];
    float x = 10.f * z2;
    float enx = fexp2(-fabsf(x) * L2E);
    float sp = (fmaxf(x, 0.f) + 0.6931471805599453f * flog2(1.f + enx)) * 0.1f;
    float iwg = cfg * frcp(fmaxf(sp, 1e-6f));
    aa[g] = iwg * S2;
    oo[g] = cfg * iwg * S2;
    float d0 = fmaf(fv0, aa[g], -oo[g]);
    float dL = fmaf(fvL, aa[g], -oo[g]);
    mxm[g] = fmaxf(d0 * d0, dL * dL);
  }

  float sm[8];
#pragma unroll
  for (int g = 0; g < 8; ++g) sm[g] = 0.f;

  // ---- single exponent pass over this wave's groups g2 = 2i+half <= 18 ----
  unsigned pk[10][4];
#pragma unroll
  for (int i = 0; i < 10; ++i) {
    int g2 = 2 * i + half;
    if (g2 <= 18) {
      int f = t + 64 * g2;
      float fv = freqs[min(f, NF - 1)];
#pragma unroll
      for (int j = 0; j < 4; ++j) {
        float d0 = fmaf(fv, aa[2 * j], -oo[2 * j]);
        float e0 = fexp2(fmaf(d0, d0, -mxm[2 * j]));
        float d1 = fmaf(fv, aa[2 * j + 1], -oo[2 * j + 1]);
        float e1 = fexp2(fmaf(d1, d1, -mxm[2 * j + 1]));
        if (g2 == 18 && t == 63) { e0 = 0.f; e1 = 0.f; }
        unsigned b0 = __builtin_bit_cast(unsigned, e0) & 0xFFFF0000u;
        unsigned b1 = __builtin_bit_cast(unsigned, e1) & 0xFFFF0000u;
        unsigned pw = b1 | (b0 >> 16);
        asm volatile("" : "+v"(pw));  // opaque: forbid remat of the exp2 chain
        pk[i][j] = pw;
        sm[2 * j]     += __builtin_bit_cast(float, b0);
        sm[2 * j + 1] += __builtin_bit_cast(float, b1);
      }
    }
  }

  // intra-wave reduce, publish partials, cross-wave combine
#pragma unroll
  for (int g = 0; g < 8; ++g)
#pragma unroll
    for (int m = 32; m >= 1; m >>= 1) sm[g] += __shfl_xor(sm[g], m);
  if (t == 0) {
#pragma unroll
    for (int g = 0; g < 8; ++g) smx[rowb][half][g] = sm[g];
  }
  __syncthreads();

  float wsn[8], wcn[8];
#pragma unroll
  for (int g = 0; g < 8; ++g) {
    float tot = smx[rowb][0][g] + smx[rowb][1][g];
    float inv = frcp(tot);
    wsn[g] = __shfl(cv, 4 * g + 0) * inv;
    wcn[g] = __shfl(cv, 4 * g + 1) * inv;
  }

  // ---- accumulate + store from packed e (this wave's groups only) ----
  size_t base = (size_t)b * KF;
#pragma unroll
  for (int i = 0; i < 10; ++i) {
    int g2 = 2 * i + half;
    if (g2 <= 18) {
      float as = 0.f, ac = 0.f;
#pragma unroll
      for (int j = 0; j < 4; ++j) {
        unsigned pw = pk[i][j];
        float e0 = __builtin_bit_cast(float, pw << 16);
        float e1 = __builtin_bit_cast(float, pw & 0xFFFF0000u);
        as = fmaf(e0, wsn[2 * j], as);
        as = fmaf(e1, wsn[2 * j + 1], as);
        ac = fmaf(e0, wcn[2 * j], ac);
        ac = fmaf(e1, wcn[2 * j + 1], ac);
      }
      int f = t + 64 * g2;
      if (f < NF) {
        amps[base + f] = f2b(as);
        amps[base + NF + f] = f2b(ac);
      }
    }
  }
  if (half == 0 && t == 0) {
    amps[base + 2430] = 0;
    amps[base + 2431] = 0;
  }
}

extern "C" void kernel_launch(void* const* d_in, const int* in_sizes, int n_in,
                              void* d_out, int out_size, void* d_ws, size_t ws_size,
                              hipStream_t stream) {
  (void)in_sizes; (void)n_in; (void)out_size; (void)ws_size;
  const float* x = (const float*)d_in[0];
  const float* fcw[4] = {(const float*)d_in[1], (const float*)d_in[3],
                         (const float*)d_in[5], (const float*)d_in[7]};
  const float* fcb[4] = {(const float*)d_in[2], (const float*)d_in[4],
                         (const float*)d_in[6], (const float*)d_in[8]};
  const float* theta_w = (const float*)d_in[9];
  const float* fn_g = (const float*)d_in[10];
  const float* fn_b = (const float*)d_in[11];
  const float* wn_g = (const float*)d_in[12];
  const float* wn_b = (const float*)d_in[13];
  const float* freqs = (const float*)d_in[14];
  const float* sb = (const float*)d_in[15];
  const float* sf = (const float*)d_in[16];
  float* out = (float*)d_out;

  char* p = (char*)d_ws;
  auto take = [&](size_t bytes) {
    char* r = p;
    p += (bytes + 255) & ~(size_t)255;
    return r;
  };
  unsigned short* h0h = (unsigned short*)take((size_t)BATCH * UNITS * 2);
  unsigned short* h0l = (unsigned short*)take((size_t)BATCH * UNITS * 2);
  unsigned short* h1h = (unsigned short*)take((size_t)BATCH * UNITS * 2);
  unsigned short* h1l = (unsigned short*)take((size_t)BATCH * UNITS * 2);
  unsigned short *wh[4], *wl[4];
  for (int l = 0; l < 4; ++l) {
    wh[l] = (unsigned short*)take((size_t)UNITS * UNITS * 2);
    wl[l] = (unsigned short*)take((size_t)UNITS * UNITS * 2);
  }
  unsigned short* twh = (unsigned short*)take((size_t)32 * UNITS * 2);
  unsigned short* twl = (unsigned short*)take((size_t)32 * UNITS * 2);
  float* coeff = (float*)take((size_t)BATCH * 32 * 4);
  unsigned short* st = (unsigned short*)take((size_t)640 * KF * 2);
  unsigned short* amps = (unsigned short*)take((size_t)BATCH * KF * 2);

  // prep
  split_k4<<<2048, 256, 0, stream>>>(x, h0h, h0l, BATCH * UNITS / 4);
  for (int l = 0; l < 4; ++l)
    split_k4<<<256, 256, 0, stream>>>(fcw[l], wh[l], wl[l], UNITS * UNITS / 4);
  split_k4<<<16, 256, 0, stream>>>(theta_w, twh, twl, 32 * UNITS / 4);
  st_prep<<<dim3(KF / 32, 640 / 32), dim3(32, 8), 0, stream>>>(sb, sf, st);

  // FC stack (split-bf16): x->h1->h0->h1->h0   (1-D grid, XCD-aware mapping)
  gemm_fc<4><<<4 * (BATCH / 128), 256, 0, stream>>>(
      h0h, h0l, wh[0], wl[0], fcb[0], h1h, h1l);
  gemm_fc<4><<<4 * (BATCH / 128), 256, 0, stream>>>(
      h1h, h1l, wh[1], wl[1], fcb[1], h0h, h0l);
  gemm_fc<4><<<4 * (BATCH / 128), 256, 0, stream>>>(
      h0h, h0l, wh[2], wl[2], fcb[2], h1h, h1l);
  gemm_fc<4><<<4 * (BATCH / 128), 256, 0, stream>>>(
      h1h, h1l, wh[3], wl[3], fcb[3], h0h, h0l);

  // theta projection
  coeff_gemm<<<BATCH / 128, 256, 0, stream>>>(h0h, h0l, twh, twl, coeff);

  // gaussian head -> amps (bf16, padded to 2432); 2 waves/row, 2 rows/block
  gauss_kernel<<<BATCH / 2, 256, 0, stream>>>(coeff, fn_g, fn_b, wn_g, wn_b, freqs, amps);

  // final GEMM -> backcast + forecast (wide tile: 128x320, 2 bn tiles)
  gemm_wide<<<2 * (BATCH / 128), 256, 0, stream>>>(amps, st, out);
}

// Round 14
// 518.850 us; speedup vs baseline: 1.0318x; 1.0046x over previous
//
#include <hip/hip_runtime.h>
#include <hip/hip_bf16.h>
#include <math.h>

#define BATCH 32768
#define UNITS 512
#define NF 1215      // number of freqs = 2L-1
#define KF 2432      // padded 2*NF
#define NOUT 608     // 512 + 96

typedef __bf16 bf16x8 __attribute__((ext_vector_type(8)));
typedef float f32x4 __attribute__((ext_vector_type(4)));
typedef short s16x4 __attribute__((ext_vector_type(4)));
typedef short s16x8 __attribute__((ext_vector_type(8)));
typedef unsigned u32x4 __attribute__((ext_vector_type(4)));

__device__ __forceinline__ unsigned short f2b(float f) {
  unsigned u = __builtin_bit_cast(unsigned, f);
  u += 0x7fffu + ((u >> 16) & 1u);
  return (unsigned short)(u >> 16);
}
__device__ __forceinline__ float b2f(unsigned short h) {
  unsigned u = ((unsigned)h) << 16;
  return __builtin_bit_cast(float, u);
}

#if __has_builtin(__builtin_amdgcn_exp2f)
__device__ __forceinline__ float fexp2(float x) { return __builtin_amdgcn_exp2f(x); }
#else
__device__ __forceinline__ float fexp2(float x) { return exp2f(x); }
#endif
#if __has_builtin(__builtin_amdgcn_logf)
__device__ __forceinline__ float flog2(float x) { return __builtin_amdgcn_logf(x); }
#else
__device__ __forceinline__ float flog2(float x) { return log2f(x); }
#endif
#if __has_builtin(__builtin_amdgcn_rcpf)
__device__ __forceinline__ float frcp(float x) { return __builtin_amdgcn_rcpf(x); }
#else
__device__ __forceinline__ float frcp(float x) { return 1.f / x; }
#endif

// async global->LDS, 16B per lane; LDS dest = wave-uniform base + lane*16
__device__ __forceinline__ void gload16(const unsigned short* g, unsigned short* l) {
  __builtin_amdgcn_global_load_lds(
      (const __attribute__((address_space(1))) void*)g,
      (__attribute__((address_space(3))) void*)l, 16, 0, 0);
}

// counted vmcnt wait (N = allowed outstanding VMEM ops), literal-templated
template <int N> __device__ __forceinline__ void wait_vm() {
  if constexpr (N == 0)      asm volatile("s_waitcnt vmcnt(0)" ::: "memory");
  else if constexpr (N == 7) asm volatile("s_waitcnt vmcnt(7)" ::: "memory");
  else                       asm volatile("s_waitcnt vmcnt(8)" ::: "memory");
}
__device__ __forceinline__ void barrier_raw() {
  asm volatile("" ::: "memory");
  __builtin_amdgcn_s_barrier();
  asm volatile("" ::: "memory");
}

// ---------- prep: split fp32 -> bf16 hi + bf16 lo (lo = round(v - hi)) ----------
__global__ __launch_bounds__(256) void split_k4(
    const float* __restrict__ src, unsigned short* __restrict__ hi,
    unsigned short* __restrict__ lo, int n4)
{
  int i = blockIdx.x * 256 + threadIdx.x;
  int stride = gridDim.x * 256;
  for (; i < n4; i += stride) {
    f32x4 v = ((const f32x4*)src)[i];
    s16x4 h, l;
#pragma unroll
    for (int j = 0; j < 4; ++j) {
      unsigned short hb = f2b(v[j]);
      h[j] = (short)hb;
      l[j] = (short)f2b(v[j] - b2f(hb));
    }
    ((s16x4*)hi)[i] = h;
    ((s16x4*)lo)[i] = l;
  }
}

// ---------- prep: st[n][k] = S[k][n] as bf16, padded to [640][2432] ----------
__global__ __launch_bounds__(256) void st_prep(
    const float* __restrict__ sb, const float* __restrict__ sf,
    unsigned short* __restrict__ st)
{
  __shared__ float tile[32][33];
  int k0 = blockIdx.x * 32, n0 = blockIdx.y * 32;
  int tx = threadIdx.x, ty = threadIdx.y;
#pragma unroll
  for (int yy = 0; yy < 32; yy += 8) {
    int k = k0 + ty + yy, n = n0 + tx;
    float v = 0.f;
    if (k < 2430) {
      if (n < 512) v = sb[(size_t)k * 512 + n];
      else if (n < NOUT) v = sf[(size_t)k * 96 + (n - 512)];
    }
    tile[ty + yy][tx] = v;
  }
  __syncthreads();
#pragma unroll
  for (int yy = 0; yy < 32; yy += 8) {
    int n = n0 + ty + yy, k = k0 + tx;
    st[(size_t)n * KF + k] = f2b(tile[tx][ty + yy]);
  }
}

// ---------- FC GEMM: C[M][512] = A[M][512] * W[512][512]^T, split-bf16 ----------
// 128x128 tile, 4 waves, NBUF=2. Per iter: STAGE(next tile, other buf) ->
// vmcnt(8) -> barrier -> compute -> barrier. NO setprio (round-9 lesson).
template <int NBN>
__global__ __launch_bounds__(256) void gemm_fc(
    const unsigned short* __restrict__ Agh, const unsigned short* __restrict__ Agl,
    const unsigned short* __restrict__ Bgh, const unsigned short* __restrict__ Bgl,
    const float* __restrict__ bias,
    unsigned short* __restrict__ Chi, unsigned short* __restrict__ Clo)
{
  constexpr int NT = 512 / 32;
  __shared__ unsigned short Ah[2][128 * 32];
  __shared__ unsigned short Bh[2][128 * 32];
  __shared__ unsigned short Al[2][128 * 32];
  __shared__ unsigned short Bl[2][128 * 32];

  const int t = threadIdx.x;
  const int lane = t & 63;
  const int w = t >> 6;
  const int wr = w >> 1, wc = w & 1;

  // XCD-aware mapping (BATCH/128 = 256 bm panels, 32 per XCD)
  const int lin = blockIdx.x;
  const int xcd = lin & 7;
  const int sub = lin >> 3;
  const long bm = (long)(xcd * 32 + sub / NBN) * 128;
  const int bn = (sub % NBN) * 128;

  const int lr = lane & 15, kg = lane >> 4;

  // staging: wave w fills windows w and w+4 (16 rows x 32 cols = 1KB each);
  // lane l -> row base+(l>>2), chunk l&3; inverse read-swizzle on global src.
  const int Rw = lane >> 2;
  const int pch = lane & 3;
  const int R1 = w * 16 + Rw;
  const int R2 = (w + 4) * 16 + Rw;
  const int s1 = (pch - (R1 >> 1)) & 3;
  const int s2 = (pch - (R2 >> 1)) & 3;
  const size_t oA1 = (size_t)(bm + R1) * UNITS + s1 * 8;
  const size_t oA2 = (size_t)(bm + R2) * UNITS + s2 * 8;
  const size_t oB1 = (size_t)(bn + R1) * UNITS + s1 * 8;
  const size_t oB2 = (size_t)(bn + R2) * UNITS + s2 * 8;

  auto STAGE = [&](int buf, int kt) {
    gload16(Agh + oA1 + kt, &Ah[buf][w * 512]);
    gload16(Agh + oA2 + kt, &Ah[buf][(w + 4) * 512]);
    gload16(Bgh + oB1 + kt, &Bh[buf][w * 512]);
    gload16(Bgh + oB2 + kt, &Bh[buf][(w + 4) * 512]);
    gload16(Agl + oA1 + kt, &Al[buf][w * 512]);
    gload16(Agl + oA2 + kt, &Al[buf][(w + 4) * 512]);
    gload16(Bgl + oB1 + kt, &Bl[buf][w * 512]);
    gload16(Bgl + oB2 + kt, &Bl[buf][(w + 4) * 512]);
  };

  const f32x4 fzero = {0.f, 0.f, 0.f, 0.f};
  f32x4 acc[4][4];
#pragma unroll
  for (int m = 0; m < 4; ++m)
#pragma unroll
    for (int n = 0; n < 4; ++n) acc[m][n] = fzero;

  STAGE(0, 0);
  int cur = 0;
  for (int it = 0; it < NT; ++it) {
    if (it + 1 < NT) { STAGE(cur ^ 1, (it + 1) * 32); wait_vm<8>(); }
    else wait_vm<0>();
    barrier_raw();  // stage(it) visible to all waves

    bf16x8 bhf[4], blf[4];
#pragma unroll
    for (int n = 0; n < 4; ++n) {
      int R = wc * 64 + n * 16 + lr;
      int phys = R * 32 + (((kg + (R >> 1)) & 3) << 3);
      bhf[n] = *(const bf16x8*)&Bh[cur][phys];
      blf[n] = *(const bf16x8*)&Bl[cur][phys];
    }
#pragma unroll
    for (int m = 0; m < 4; ++m) {
      int R = wr * 64 + m * 16 + lr;
      int phys = R * 32 + (((kg + (R >> 1)) & 3) << 3);
      bf16x8 ahf = *(const bf16x8*)&Ah[cur][phys];
      bf16x8 alf = *(const bf16x8*)&Al[cur][phys];
#pragma unroll
      for (int n = 0; n < 4; ++n) {
        acc[m][n] = __builtin_amdgcn_mfma_f32_16x16x32_bf16(ahf, bhf[n], acc[m][n], 0, 0, 0);
        acc[m][n] = __builtin_amdgcn_mfma_f32_16x16x32_bf16(ahf, blf[n], acc[m][n], 0, 0, 0);
        acc[m][n] = __builtin_amdgcn_mfma_f32_16x16x32_bf16(alf, bhf[n], acc[m][n], 0, 0, 0);
      }
    }
    barrier_raw();  // reads of buf `cur` done before next iter re-stages it
    cur ^= 1;
  }

  // epilogue: C/D layout col=lane&15, row=(lane>>4)*4+reg
#pragma unroll
  for (int m = 0; m < 4; ++m) {
#pragma unroll
    for (int n = 0; n < 4; ++n) {
      long gr0 = bm + wr * 64 + m * 16 + kg * 4;
      int gc = bn + wc * 64 + n * 16 + lr;
      float bv = bias[gc];
#pragma unroll
      for (int r = 0; r < 4; ++r) {
        float o = fmaxf(acc[m][n][r] + bv, 0.f);
        unsigned short h = f2b(o);
        size_t off = (size_t)(gr0 + r) * UNITS + gc;
        Chi[off] = h;
        Clo[off] = f2b(o - b2f(h));
      }
    }
  }
}

// ---------- final GEMM: out[M][608] = amps[M][KF] * st[640][KF]^T, plain bf16 ----
// WIDE tile: BM=128, BN=320, 4 waves, wave = 64x160, 40 MFMA/period.
// Uniform NBUF=2 staged A+B (round-10 best). LDS 56KB -> 2 blocks/CU;
// grid = 512 = exactly 2/CU. launch_bounds(256,2) pins regalloc.
__global__ __launch_bounds__(256, 2) void gemm_wide(
    const unsigned short* __restrict__ Ag, const unsigned short* __restrict__ Bg,
    float* __restrict__ outF)
{
  constexpr int NT = KF / 32;  // 76
  __shared__ unsigned short Ah[2][128 * 32];
  __shared__ unsigned short Bh[2][320 * 32];

  const int t = threadIdx.x;
  const int lane = t & 63;
  const int w = t >> 6;
  const int wr = w >> 1, wc = w & 1;

  // XCD mapping: 256 bm panels x 2 bn tiles; 32 panels per XCD
  const int lin = blockIdx.x;
  const int xcd = lin & 7;
  const int sub = lin >> 3;           // 0..63
  const long bm = (long)(xcd * 32 + (sub >> 1)) * 128;
  const int bn = (sub & 1) * 320;

  const int lr = lane & 15, kg = lane >> 4;
  const int Rl = lane >> 2, pch = lane & 3;

  // A: 8 windows; wave w stages windows w, w+4
  const int RA1 = w * 16 + Rl, RA2 = (w + 4) * 16 + Rl;
  const int sA1 = (pch - (RA1 >> 1)) & 3, sA2 = (pch - (RA2 >> 1)) & 3;
  const size_t oA1 = (size_t)(bm + RA1) * KF + sA1 * 8;
  const size_t oA2 = (size_t)(bm + RA2) * KF + sA2 * 8;
  // B: 20 windows; wave w stages windows w*5 .. w*5+4
  size_t oB[5];
#pragma unroll
  for (int j = 0; j < 5; ++j) {
    int q = w * 5 + j;
    int R = q * 16 + Rl;
    int s = (pch - (R >> 1)) & 3;
    oB[j] = (size_t)(bn + R) * KF + s * 8;
  }

  auto STAGE = [&](int buf, int kt) {
    gload16(Ag + oA1 + kt, &Ah[buf][w * 512]);
    gload16(Ag + oA2 + kt, &Ah[buf][(w + 4) * 512]);
#pragma unroll
    for (int j = 0; j < 5; ++j)
      gload16(Bg + oB[j] + kt, &Bh[buf][(w * 5 + j) * 512]);
  };

  const f32x4 fzero = {0.f, 0.f, 0.f, 0.f};
  f32x4 acc[4][10];
#pragma unroll
  for (int m = 0; m < 4; ++m)
#pragma unroll
    for (int n = 0; n < 10; ++n) acc[m][n] = fzero;

  STAGE(0, 0);
  int cur = 0;
  for (int it = 0; it < NT; ++it) {
    if (it + 1 < NT) { STAGE(cur ^ 1, (it + 1) * 32); wait_vm<7>(); }
    else wait_vm<0>();
    barrier_raw();

    bf16x8 af[4];
#pragma unroll
    for (int m = 0; m < 4; ++m) {
      int R = wr * 64 + m * 16 + lr;
      af[m] = *(const bf16x8*)&Ah[cur][R * 32 + (((kg + (R >> 1)) & 3) << 3)];
    }
#pragma unroll
    for (int n = 0; n < 10; ++n) {
      int R = wc * 160 + n * 16 + lr;
      bf16x8 bf = *(const bf16x8*)&Bh[cur][R * 32 + (((kg + (R >> 1)) & 3) << 3)];
#pragma unroll
      for (int m = 0; m < 4; ++m)
        acc[m][n] = __builtin_amdgcn_mfma_f32_16x16x32_bf16(af[m], bf, acc[m][n], 0, 0, 0);
    }
    barrier_raw();
    cur ^= 1;
  }

  // epilogue
#pragma unroll
  for (int m = 0; m < 4; ++m) {
#pragma unroll
    for (int n = 0; n < 10; ++n) {
      long gr0 = bm + wr * 64 + m * 16 + kg * 4;
      int gc = bn + wc * 160 + n * 16 + lr;
      if (gc < NOUT) {
#pragma unroll
        for (int r = 0; r < 4; ++r) {
          float o = acc[m][n][r];
          long row = gr0 + r;
          if (gc < 512) outF[row * 512 + gc] = o;
          else outF[(size_t)BATCH * 512 + row * 96 + (gc - 512)] = o;
        }
      }
    }
  }
}

// ---------- theta projection: coeff[M][32] = h3[M][512] * theta_w[32][512]^T, split-bf16 ----------
__global__ __launch_bounds__(256) void coeff_gemm(
    const unsigned short* __restrict__ Agh, const unsigned short* __restrict__ Agl,
    const unsigned short* __restrict__ Bgh, const unsigned short* __restrict__ Bgl,
    float* __restrict__ coeff)
{
  __shared__ unsigned short Ah[128 * 32];
  __shared__ unsigned short Al[128 * 32];
  __shared__ unsigned short Bh[32 * 32];
  __shared__ unsigned short Bl[32 * 32];

  const int t = threadIdx.x;
  const int lane = t & 63;
  const int w = t >> 6;
  const long bm = (long)blockIdx.x * 128;
  const int lr = lane & 15, kg = lane >> 4;

  const f32x4 fzero = {0.f, 0.f, 0.f, 0.f};
  f32x4 acc[2][2];
#pragma unroll
  for (int m = 0; m < 2; ++m)
#pragma unroll
    for (int n = 0; n < 2; ++n) acc[m][n] = fzero;

  for (int kt = 0; kt < 512; kt += 32) {
    __syncthreads();
#pragma unroll
    for (int p = 0; p < 2; ++p) {
      int c = t + 256 * p;
      int row = c >> 2, slot = c & 3;
      int phys = row * 32 + (((slot + (row >> 1)) & 3) << 3);
      size_t go = (size_t)(bm + row) * UNITS + kt + slot * 8;
      *(s16x8*)&Ah[phys] = *(const s16x8*)&Agh[go];
      *(s16x8*)&Al[phys] = *(const s16x8*)&Agl[go];
    }
    if (t < 128) {
      int row = t >> 2, slot = t & 3;
      int phys = row * 32 + (((slot + (row >> 1)) & 3) << 3);
      size_t go = (size_t)row * UNITS + kt + slot * 8;
      *(s16x8*)&Bh[phys] = *(const s16x8*)&Bgh[go];
      *(s16x8*)&Bl[phys] = *(const s16x8*)&Bgl[go];
    }
    __syncthreads();

    bf16x8 bh[2], bl[2];
#pragma unroll
    for (int n = 0; n < 2; ++n) {
      int R = n * 16 + lr;
      int phys = R * 32 + (((kg + (R >> 1)) & 3) << 3);
      bh[n] = *(const bf16x8*)&Bh[phys];
      bl[n] = *(const bf16x8*)&Bl[phys];
    }
#pragma unroll
    for (int m = 0; m < 2; ++m) {
      int R = w * 32 + m * 16 + lr;
      int phys = R * 32 + (((kg + (R >> 1)) & 3) << 3);
      bf16x8 ah = *(const bf16x8*)&Ah[phys];
      bf16x8 al = *(const bf16x8*)&Al[phys];
#pragma unroll
      for (int n = 0; n < 2; ++n) {
        acc[m][n] = __builtin_amdgcn_mfma_f32_16x16x32_bf16(ah, bh[n], acc[m][n], 0, 0, 0);
        acc[m][n] = __builtin_amdgcn_mfma_f32_16x16x32_bf16(ah, bl[n], acc[m][n], 0, 0, 0);
        acc[m][n] = __builtin_amdgcn_mfma_f32_16x16x32_bf16(al, bh[n], acc[m][n], 0, 0, 0);
      }
    }
  }
#pragma unroll
  for (int m = 0; m < 2; ++m)
#pragma unroll
    for (int n = 0; n < 2; ++n) {
      long gr0 = bm + w * 32 + m * 16 + kg * 4;
      int gc = n * 16 + lr;
#pragma unroll
      for (int r = 0; r < 4; ++r)
        coeff[(size_t)(gr0 + r) * 32 + gc] = acc[m][n][r];
    }
}

// ---------- gaussian head: 1 wave/row, 2 rows per 128-thread block ----------
// SINGLE exp2 pass with packed-e spill target = LDS, not VGPRs: round 13
// showed VGPR=48 with 40 opaque pk regs -> scratch-spill storm. Each wave
// owns a private 19KB LDS region [19][64 lanes][16B]; pass 1 packs 8 bf16-e
// into 4 u32 and does ONE ds_write_b128 per group; pass 2 reads them back.
// Contiguous 16B/lane = dense conflict-free LDS pattern. Live regs ~75 ->
// no spills. sm accumulated from the SAME truncated values (consistent
// renorm, round-10 absmax). No barriers (waves independent). Closed-form
// softmax max via endpoint convexity; hw trans pipe; base-2 softmax:
// exp(0.5*d^2)==2^((d*s)^2), s=sqrt(0.5*log2e).
__global__ __launch_bounds__(128) void gauss_kernel(
    const float* __restrict__ coeff, const float* __restrict__ fn_g,
    const float* __restrict__ fn_b, const float* __restrict__ wn_g,
    const float* __restrict__ wn_b, const float* __restrict__ freqs,
    unsigned short* __restrict__ amps)
{
  __shared__ u32x4 pkL[2][19][64];   // 38,912 B -> 4 blocks/CU (8 waves)
  const int wid = threadIdx.x >> 6;  // 0..1
  const int t = threadIdx.x & 63;
  const int b = blockIdx.x * 2 + wid;
  const float cv = coeff[(size_t)b * 32 + (t & 31)];
  const float L2E = 1.4426950408889634f;

  float c2[8], c3[8];
  float m2 = 0.f, m3 = 0.f;
#pragma unroll
  for (int g = 0; g < 8; ++g) {
    c2[g] = __shfl(cv, 4 * g + 2);
    c3[g] = __shfl(cv, 4 * g + 3);
    m2 += c2[g]; m3 += c3[g];
  }
  m2 *= 0.125f; m3 *= 0.125f;
  float v2 = 0.f, v3 = 0.f;
#pragma unroll
  for (int g = 0; g < 8; ++g) {
    float d2 = c2[g] - m2; v2 += d2 * d2;
    float d3 = c3[g] - m3; v3 += d3 * d3;
  }
  v2 *= 0.125f; v3 *= 0.125f;
  const float r2 = rsqrtf(v2 + 1e-5f), r3 = rsqrtf(v3 + 1e-5f);

  const float S2 = 0.8493218f;  // sqrt(0.5 * log2(e))
  const float fv0 = freqs[0], fvL = freqs[NF - 1];
  float aa[8], oo[8], mxm[8];
#pragma unroll
  for (int g = 0; g < 8; ++g) {
    float z3 = (c3[g] - m3) * r3 * fn_g[g] + fn_b[g];
    float sig = frcp(1.f + fexp2(-z3 * L2E));
    float cfg = frcp(1.f + sig * 608.f);
    float z2 = (c2[g] - m2) * r2 * wn_g[g] + wn_b[g];
    float x = 10.f * z2;
    float enx = fexp2(-fabsf(x) * L2E);
    float sp = (fmaxf(x, 0.f) + 0.6931471805599453f * flog2(1.f + enx)) * 0.1f;
    float iwg = cfg * frcp(fmaxf(sp, 1e-6f));
    aa[g] = iwg * S2;
    oo[g] = cfg * iwg * S2;
    float d0 = fmaf(fv0, aa[g], -oo[g]);
    float dL = fmaf(fvL, aa[g], -oo[g]);
    mxm[g] = fmaxf(d0 * d0, dL * dL);
  }

  float sm[8];
#pragma unroll
  for (int g = 0; g < 8; ++g) sm[g] = 0.f;

  // ---- single exponent pass: compute e, truncate to bf16, pack, park in LDS ----
#pragma unroll
  for (int i = 0; i < 19; ++i) {
    int f = t + 64 * i;
    float fv = freqs[min(f, NF - 1)];
    u32x4 pw;
#pragma unroll
    for (int j = 0; j < 4; ++j) {
      float d0 = fmaf(fv, aa[2 * j], -oo[2 * j]);
      float e0 = fexp2(fmaf(d0, d0, -mxm[2 * j]));
      float d1 = fmaf(fv, aa[2 * j + 1], -oo[2 * j + 1]);
      float e1 = fexp2(fmaf(d1, d1, -mxm[2 * j + 1]));
      if (i == 18 && t == 63) { e0 = 0.f; e1 = 0.f; }
      unsigned b0 = __builtin_bit_cast(unsigned, e0) & 0xFFFF0000u;
      unsigned b1 = __builtin_bit_cast(unsigned, e1) & 0xFFFF0000u;
      pw[j] = b1 | (b0 >> 16);
      sm[2 * j]     += __builtin_bit_cast(float, b0);
      sm[2 * j + 1] += __builtin_bit_cast(float, b1);
    }
    pkL[wid][i][t] = pw;  // one ds_write_b128
  }

  float wsn[8], wcn[8];
#pragma unroll
  for (int g = 0; g < 8; ++g) {
#pragma unroll
    for (int m = 32; m >= 1; m >>= 1) sm[g] += __shfl_xor(sm[g], m);
    float inv = frcp(sm[g]);
    wsn[g] = __shfl(cv, 4 * g + 0) * inv;
    wcn[g] = __shfl(cv, 4 * g + 1) * inv;
  }

  // ---- accumulate + store from LDS-parked packed e ----
  size_t base = (size_t)b * KF;
#pragma unroll
  for (int i = 0; i < 19; ++i) {
    u32x4 pw = pkL[wid][i][t];  // one ds_read_b128
    float as = 0.f, ac = 0.f;
#pragma unroll
    for (int j = 0; j < 4; ++j) {
      float e0 = __builtin_bit_cast(float, pw[j] << 16);
      float e1 = __builtin_bit_cast(float, pw[j] & 0xFFFF0000u);
      as = fmaf(e0, wsn[2 * j], as);
      as = fmaf(e1, wsn[2 * j + 1], as);
      ac = fmaf(e0, wcn[2 * j], ac);
      ac = fmaf(e1, wcn[2 * j + 1], ac);
    }
    int f = t + 64 * i;
    if (f < NF) {
      amps[base + f] = f2b(as);
      amps[base + NF + f] = f2b(ac);
    }
  }
  if (t == 0) {
    amps[base + 2430] = 0;
    amps[base + 2431] = 0;
  }
}

extern "C" void kernel_launch(void* const* d_in, const int* in_sizes, int n_in,
                              void* d_out, int out_size, void* d_ws, size_t ws_size,
                              hipStream_t stream) {
  (void)in_sizes; (void)n_in; (void)out_size; (void)ws_size;
  const float* x = (const float*)d_in[0];
  const float* fcw[4] = {(const float*)d_in[1], (const float*)d_in[3],
                         (const float*)d_in[5], (const float*)d_in[7]};
  const float* fcb[4] = {(const float*)d_in[2], (const float*)d_in[4],
                         (const float*)d_in[6], (const float*)d_in[8]};
  const float* theta_w = (const float*)d_in[9];
  const float* fn_g = (const float*)d_in[10];
  const float* fn_b = (const float*)d_in[11];
  const float* wn_g = (const float*)d_in[12];
  const float* wn_b = (const float*)d_in[13];
  const float* freqs = (const float*)d_in[14];
  const float* sb = (const float*)d_in[15];
  const float* sf = (const float*)d_in[16];
  float* out = (float*)d_out;

  char* p = (char*)d_ws;
  auto take = [&](size_t bytes) {
    char* r = p;
    p += (bytes + 255) & ~(size_t)255;
    return r;
  };
  unsigned short* h0h = (unsigned short*)take((size_t)BATCH * UNITS * 2);
  unsigned short* h0l = (unsigned short*)take((size_t)BATCH * UNITS * 2);
  unsigned short* h1h = (unsigned short*)take((size_t)BATCH * UNITS * 2);
  unsigned short* h1l = (unsigned short*)take((size_t)BATCH * UNITS * 2);
  unsigned short *wh[4], *wl[4];
  for (int l = 0; l < 4; ++l) {
    wh[l] = (unsigned short*)take((size_t)UNITS * UNITS * 2);
    wl[l] = (unsigned short*)take((size_t)UNITS * UNITS * 2);
  }
  unsigned short* twh = (unsigned short*)take((size_t)32 * UNITS * 2);
  unsigned short* twl = (unsigned short*)take((size_t)32 * UNITS * 2);
  float* coeff = (float*)take((size_t)BATCH * 32 * 4);
  unsigned short* st = (unsigned short*)take((size_t)640 * KF * 2);
  unsigned short* amps = (unsigned short*)take((size_t)BATCH * KF * 2);

  // prep
  split_k4<<<2048, 256, 0, stream>>>(x, h0h, h0l, BATCH * UNITS / 4);
  for (int l = 0; l < 4; ++l)
    split_k4<<<256, 256, 0, stream>>>(fcw[l], wh[l], wl[l], UNITS * UNITS / 4);
  split_k4<<<16, 256, 0, stream>>>(theta_w, twh, twl, 32 * UNITS / 4);
  st_prep<<<dim3(KF / 32, 640 / 32), dim3(32, 8), 0, stream>>>(sb, sf, st);

  // FC stack (split-bf16): x->h1->h0->h1->h0   (1-D grid, XCD-aware mapping)
  gemm_fc<4><<<4 * (BATCH / 128), 256, 0, stream>>>(
      h0h, h0l, wh[0], wl[0], fcb[0], h1h, h1l);
  gemm_fc<4><<<4 * (BATCH / 128), 256, 0, stream>>>(
      h1h, h1l, wh[1], wl[1], fcb[1], h0h, h0l);
  gemm_fc<4><<<4 * (BATCH / 128), 256, 0, stream>>>(
      h0h, h0l, wh[2], wl[2], fcb[2], h1h, h1l);
  gemm_fc<4><<<4 * (BATCH / 128), 256, 0, stream>>>(
      h1h, h1l, wh[3], wl[3], fcb[3], h0h, h0l);

  // theta projection
  coeff_gemm<<<BATCH / 128, 256, 0, stream>>>(h0h, h0l, twh, twl, coeff);

  // gaussian head -> amps (bf16, padded to 2432); 1 wave/row, 2 rows/block
  gauss_kernel<<<BATCH / 2, 128, 0, stream>>>(coeff, fn_g, fn_b, wn_g, wn_b, freqs, amps);

  // final GEMM -> backcast + forecast (wide tile: 128x320, 2 bn tiles)
  gemm_wide<<<2 * (BATCH / 128), 256, 0, stream>>>(amps, st, out);
}

// Round 15
// 513.838 us; speedup vs baseline: 1.0419x; 1.0098x over previous
//
#include <hip/hip_runtime.h>
#include <hip/hip_bf16.h>
#include <math.h>

#define BATCH 32768
#define UNITS 512
#define NF 1215      // number of freqs = 2L-1
#define KF 2432      // padded 2*NF
#define NOUT 608     // 512 + 96

typedef __bf16 bf16x8 __attribute__((ext_vector_type(8)));
typedef float f32x4 __attribute__((ext_vector_type(4)));
typedef float f32x2 __attribute__((ext_vector_type(2)));
typedef short s16x4 __attribute__((ext_vector_type(4)));
typedef short s16x8 __attribute__((ext_vector_type(8)));
typedef unsigned u32x4 __attribute__((ext_vector_type(4)));

__device__ __forceinline__ unsigned short f2b(float f) {
  unsigned u = __builtin_bit_cast(unsigned, f);
  u += 0x7fffu + ((u >> 16) & 1u);
  return (unsigned short)(u >> 16);
}
__device__ __forceinline__ float b2f(unsigned short h) {
  unsigned u = ((unsigned)h) << 16;
  return __builtin_bit_cast(float, u);
}

#if __has_builtin(__builtin_amdgcn_exp2f)
__device__ __forceinline__ float fexp2(float x) { return __builtin_amdgcn_exp2f(x); }
#else
__device__ __forceinline__ float fexp2(float x) { return exp2f(x); }
#endif
#if __has_builtin(__builtin_amdgcn_logf)
__device__ __forceinline__ float flog2(float x) { return __builtin_amdgcn_logf(x); }
#else
__device__ __forceinline__ float flog2(float x) { return log2f(x); }
#endif
#if __has_builtin(__builtin_amdgcn_rcpf)
__device__ __forceinline__ float frcp(float x) { return __builtin_amdgcn_rcpf(x); }
#else
__device__ __forceinline__ float frcp(float x) { return 1.f / x; }
#endif

// async global->LDS, 16B per lane; LDS dest = wave-uniform base + lane*16
__device__ __forceinline__ void gload16(const unsigned short* g, unsigned short* l) {
  __builtin_amdgcn_global_load_lds(
      (const __attribute__((address_space(1))) void*)g,
      (__attribute__((address_space(3))) void*)l, 16, 0, 0);
}

// counted vmcnt wait (N = allowed outstanding VMEM ops), literal-templated
template <int N> __device__ __forceinline__ void wait_vm() {
  if constexpr (N == 0)      asm volatile("s_waitcnt vmcnt(0)" ::: "memory");
  else if constexpr (N == 7) asm volatile("s_waitcnt vmcnt(7)" ::: "memory");
  else                       asm volatile("s_waitcnt vmcnt(8)" ::: "memory");
}
__device__ __forceinline__ void barrier_raw() {
  asm volatile("" ::: "memory");
  __builtin_amdgcn_s_barrier();
  asm volatile("" ::: "memory");
}

// ---------- prep: split fp32 -> bf16 hi + bf16 lo, ALL tensors in one launch ----
struct SplitSeg { const float* src; unsigned short* hi; unsigned short* lo; unsigned n4; };
struct SplitArgs { SplitSeg seg[6]; unsigned total4; };

__global__ __launch_bounds__(256) void split_all(SplitArgs a)
{
  unsigned i = blockIdx.x * 256 + threadIdx.x;
  const unsigned stride = gridDim.x * 256;
  for (; i < a.total4; i += stride) {
    unsigned rem = i;
#pragma unroll
    for (int s = 0; s < 6; ++s) {
      if (rem < a.seg[s].n4) {
        f32x4 v = ((const f32x4*)a.seg[s].src)[rem];
        s16x4 h, l;
#pragma unroll
        for (int j = 0; j < 4; ++j) {
          unsigned short hb = f2b(v[j]);
          h[j] = (short)hb;
          l[j] = (short)f2b(v[j] - b2f(hb));
        }
        ((s16x4*)a.seg[s].hi)[rem] = h;
        ((s16x4*)a.seg[s].lo)[rem] = l;
        break;
      }
      rem -= a.seg[s].n4;
    }
  }
}

// ---------- prep: st[n][k] = S[k][n] as bf16, padded to [640][2432] ----------
__global__ __launch_bounds__(256) void st_prep(
    const float* __restrict__ sb, const float* __restrict__ sf,
    unsigned short* __restrict__ st)
{
  __shared__ float tile[32][33];
  int k0 = blockIdx.x * 32, n0 = blockIdx.y * 32;
  int tx = threadIdx.x, ty = threadIdx.y;
#pragma unroll
  for (int yy = 0; yy < 32; yy += 8) {
    int k = k0 + ty + yy, n = n0 + tx;
    float v = 0.f;
    if (k < 2430) {
      if (n < 512) v = sb[(size_t)k * 512 + n];
      else if (n < NOUT) v = sf[(size_t)k * 96 + (n - 512)];
    }
    tile[ty + yy][tx] = v;
  }
  __syncthreads();
#pragma unroll
  for (int yy = 0; yy < 32; yy += 8) {
    int n = n0 + ty + yy, k = k0 + tx;
    st[(size_t)n * KF + k] = f2b(tile[tx][ty + yy]);
  }
}

// ---------- FC GEMM: C[M][512] = A[M][512] * W[512][512]^T, split-bf16 ----------
// 128x128 tile, 4 waves, NBUF=2. Per iter: STAGE(next tile, other buf) ->
// vmcnt(8) -> barrier -> compute -> barrier. NO setprio (round-9 lesson).
template <int NBN>
__global__ __launch_bounds__(256) void gemm_fc(
    const unsigned short* __restrict__ Agh, const unsigned short* __restrict__ Agl,
    const unsigned short* __restrict__ Bgh, const unsigned short* __restrict__ Bgl,
    const float* __restrict__ bias,
    unsigned short* __restrict__ Chi, unsigned short* __restrict__ Clo)
{
  constexpr int NT = 512 / 32;
  __shared__ unsigned short Ah[2][128 * 32];
  __shared__ unsigned short Bh[2][128 * 32];
  __shared__ unsigned short Al[2][128 * 32];
  __shared__ unsigned short Bl[2][128 * 32];

  const int t = threadIdx.x;
  const int lane = t & 63;
  const int w = t >> 6;
  const int wr = w >> 1, wc = w & 1;

  // XCD-aware mapping (BATCH/128 = 256 bm panels, 32 per XCD)
  const int lin = blockIdx.x;
  const int xcd = lin & 7;
  const int sub = lin >> 3;
  const long bm = (long)(xcd * 32 + sub / NBN) * 128;
  const int bn = (sub % NBN) * 128;

  const int lr = lane & 15, kg = lane >> 4;

  // staging: wave w fills windows w and w+4 (16 rows x 32 cols = 1KB each);
  // lane l -> row base+(l>>2), chunk l&3; inverse read-swizzle on global src.
  const int Rw = lane >> 2;
  const int pch = lane & 3;
  const int R1 = w * 16 + Rw;
  const int R2 = (w + 4) * 16 + Rw;
  const int s1 = (pch - (R1 >> 1)) & 3;
  const int s2 = (pch - (R2 >> 1)) & 3;
  const size_t oA1 = (size_t)(bm + R1) * UNITS + s1 * 8;
  const size_t oA2 = (size_t)(bm + R2) * UNITS + s2 * 8;
  const size_t oB1 = (size_t)(bn + R1) * UNITS + s1 * 8;
  const size_t oB2 = (size_t)(bn + R2) * UNITS + s2 * 8;

  auto STAGE = [&](int buf, int kt) {
    gload16(Agh + oA1 + kt, &Ah[buf][w * 512]);
    gload16(Agh + oA2 + kt, &Ah[buf][(w + 4) * 512]);
    gload16(Bgh + oB1 + kt, &Bh[buf][w * 512]);
    gload16(Bgh + oB2 + kt, &Bh[buf][(w + 4) * 512]);
    gload16(Agl + oA1 + kt, &Al[buf][w * 512]);
    gload16(Agl + oA2 + kt, &Al[buf][(w + 4) * 512]);
    gload16(Bgl + oB1 + kt, &Bl[buf][w * 512]);
    gload16(Bgl + oB2 + kt, &Bl[buf][(w + 4) * 512]);
  };

  const f32x4 fzero = {0.f, 0.f, 0.f, 0.f};
  f32x4 acc[4][4];
#pragma unroll
  for (int m = 0; m < 4; ++m)
#pragma unroll
    for (int n = 0; n < 4; ++n) acc[m][n] = fzero;

  STAGE(0, 0);
  int cur = 0;
  for (int it = 0; it < NT; ++it) {
    if (it + 1 < NT) { STAGE(cur ^ 1, (it + 1) * 32); wait_vm<8>(); }
    else wait_vm<0>();
    barrier_raw();  // stage(it) visible to all waves

    bf16x8 bhf[4], blf[4];
#pragma unroll
    for (int n = 0; n < 4; ++n) {
      int R = wc * 64 + n * 16 + lr;
      int phys = R * 32 + (((kg + (R >> 1)) & 3) << 3);
      bhf[n] = *(const bf16x8*)&Bh[cur][phys];
      blf[n] = *(const bf16x8*)&Bl[cur][phys];
    }
#pragma unroll
    for (int m = 0; m < 4; ++m) {
      int R = wr * 64 + m * 16 + lr;
      int phys = R * 32 + (((kg + (R >> 1)) & 3) << 3);
      bf16x8 ahf = *(const bf16x8*)&Ah[cur][phys];
      bf16x8 alf = *(const bf16x8*)&Al[cur][phys];
#pragma unroll
      for (int n = 0; n < 4; ++n) {
        acc[m][n] = __builtin_amdgcn_mfma_f32_16x16x32_bf16(ahf, bhf[n], acc[m][n], 0, 0, 0);
        acc[m][n] = __builtin_amdgcn_mfma_f32_16x16x32_bf16(ahf, blf[n], acc[m][n], 0, 0, 0);
        acc[m][n] = __builtin_amdgcn_mfma_f32_16x16x32_bf16(alf, bhf[n], acc[m][n], 0, 0, 0);
      }
    }
    barrier_raw();  // reads of buf `cur` done before next iter re-stages it
    cur ^= 1;
  }

  // epilogue: C/D layout col=lane&15, row=(lane>>4)*4+reg
#pragma unroll
  for (int m = 0; m < 4; ++m) {
#pragma unroll
    for (int n = 0; n < 4; ++n) {
      long gr0 = bm + wr * 64 + m * 16 + kg * 4;
      int gc = bn + wc * 64 + n * 16 + lr;
      float bv = bias[gc];
#pragma unroll
      for (int r = 0; r < 4; ++r) {
        float o = fmaxf(acc[m][n][r] + bv, 0.f);
        unsigned short h = f2b(o);
        size_t off = (size_t)(gr0 + r) * UNITS + gc;
        Chi[off] = h;
        Clo[off] = f2b(o - b2f(h));
      }
    }
  }
}

// ---------- final GEMM: out[M][608] = amps[M][KF] * st[640][KF]^T, plain bf16 ----
// WIDE tile: BM=128, BN=320, 4 waves, wave = 64x160, 40 MFMA/period.
// Uniform NBUF=2 staged A+B (round-10 best). LDS 56KB -> 2 blocks/CU;
// grid = 512 = exactly 2/CU. launch_bounds(256,2) pins regalloc.
__global__ __launch_bounds__(256, 2) void gemm_wide(
    const unsigned short* __restrict__ Ag, const unsigned short* __restrict__ Bg,
    float* __restrict__ outF)
{
  constexpr int NT = KF / 32;  // 76
  __shared__ unsigned short Ah[2][128 * 32];
  __shared__ unsigned short Bh[2][320 * 32];

  const int t = threadIdx.x;
  const int lane = t & 63;
  const int w = t >> 6;
  const int wr = w >> 1, wc = w & 1;

  // XCD mapping: 256 bm panels x 2 bn tiles; 32 panels per XCD
  const int lin = blockIdx.x;
  const int xcd = lin & 7;
  const int sub = lin >> 3;           // 0..63
  const long bm = (long)(xcd * 32 + (sub >> 1)) * 128;
  const int bn = (sub & 1) * 320;

  const int lr = lane & 15, kg = lane >> 4;
  const int Rl = lane >> 2, pch = lane & 3;

  // A: 8 windows; wave w stages windows w, w+4
  const int RA1 = w * 16 + Rl, RA2 = (w + 4) * 16 + Rl;
  const int sA1 = (pch - (RA1 >> 1)) & 3, sA2 = (pch - (RA2 >> 1)) & 3;
  const size_t oA1 = (size_t)(bm + RA1) * KF + sA1 * 8;
  const size_t oA2 = (size_t)(bm + RA2) * KF + sA2 * 8;
  // B: 20 windows; wave w stages windows w*5 .. w*5+4
  size_t oB[5];
#pragma unroll
  for (int j = 0; j < 5; ++j) {
    int q = w * 5 + j;
    int R = q * 16 + Rl;
    int s = (pch - (R >> 1)) & 3;
    oB[j] = (size_t)(bn + R) * KF + s * 8;
  }

  auto STAGE = [&](int buf, int kt) {
    gload16(Ag + oA1 + kt, &Ah[buf][w * 512]);
    gload16(Ag + oA2 + kt, &Ah[buf][(w + 4) * 512]);
#pragma unroll
    for (int j = 0; j < 5; ++j)
      gload16(Bg + oB[j] + kt, &Bh[buf][(w * 5 + j) * 512]);
  };

  const f32x4 fzero = {0.f, 0.f, 0.f, 0.f};
  f32x4 acc[4][10];
#pragma unroll
  for (int m = 0; m < 4; ++m)
#pragma unroll
    for (int n = 0; n < 10; ++n) acc[m][n] = fzero;

  STAGE(0, 0);
  int cur = 0;
  for (int it = 0; it < NT; ++it) {
    if (it + 1 < NT) { STAGE(cur ^ 1, (it + 1) * 32); wait_vm<7>(); }
    else wait_vm<0>();
    barrier_raw();

    bf16x8 af[4];
#pragma unroll
    for (int m = 0; m < 4; ++m) {
      int R = wr * 64 + m * 16 + lr;
      af[m] = *(const bf16x8*)&Ah[cur][R * 32 + (((kg + (R >> 1)) & 3) << 3)];
    }
#pragma unroll
    for (int n = 0; n < 10; ++n) {
      int R = wc * 160 + n * 16 + lr;
      bf16x8 bf = *(const bf16x8*)&Bh[cur][R * 32 + (((kg + (R >> 1)) & 3) << 3)];
#pragma unroll
      for (int m = 0; m < 4; ++m)
        acc[m][n] = __builtin_amdgcn_mfma_f32_16x16x32_bf16(af[m], bf, acc[m][n], 0, 0, 0);
    }
    barrier_raw();
    cur ^= 1;
  }

  // epilogue
#pragma unroll
  for (int m = 0; m < 4; ++m) {
#pragma unroll
    for (int n = 0; n < 10; ++n) {
      long gr0 = bm + wr * 64 + m * 16 + kg * 4;
      int gc = bn + wc * 160 + n * 16 + lr;
      if (gc < NOUT) {
#pragma unroll
        for (int r = 0; r < 4; ++r) {
          float o = acc[m][n][r];
          long row = gr0 + r;
          if (gc < 512) outF[row * 512 + gc] = o;
          else outF[(size_t)BATCH * 512 + row * 96 + (gc - 512)] = o;
        }
      }
    }
  }
}

// ---------- theta projection: coeff[M][32] = h3[M][512] * theta_w[32][512]^T, split-bf16 ----------
__global__ __launch_bounds__(256) void coeff_gemm(
    const unsigned short* __restrict__ Agh, const unsigned short* __restrict__ Agl,
    const unsigned short* __restrict__ Bgh, const unsigned short* __restrict__ Bgl,
    float* __restrict__ coeff)
{
  __shared__ unsigned short Ah[128 * 32];
  __shared__ unsigned short Al[128 * 32];
  __shared__ unsigned short Bh[32 * 32];
  __shared__ unsigned short Bl[32 * 32];

  const int t = threadIdx.x;
  const int lane = t & 63;
  const int w = t >> 6;
  const long bm = (long)blockIdx.x * 128;
  const int lr = lane & 15, kg = lane >> 4;

  const f32x4 fzero = {0.f, 0.f, 0.f, 0.f};
  f32x4 acc[2][2];
#pragma unroll
  for (int m = 0; m < 2; ++m)
#pragma unroll
    for (int n = 0; n < 2; ++n) acc[m][n] = fzero;

  for (int kt = 0; kt < 512; kt += 32) {
    __syncthreads();
#pragma unroll
    for (int p = 0; p < 2; ++p) {
      int c = t + 256 * p;
      int row = c >> 2, slot = c & 3;
      int phys = row * 32 + (((slot + (row >> 1)) & 3) << 3);
      size_t go = (size_t)(bm + row) * UNITS + kt + slot * 8;
      *(s16x8*)&Ah[phys] = *(const s16x8*)&Agh[go];
      *(s16x8*)&Al[phys] = *(const s16x8*)&Agl[go];
    }
    if (t < 128) {
      int row = t >> 2, slot = t & 3;
      int phys = row * 32 + (((slot + (row >> 1)) & 3) << 3);
      size_t go = (size_t)row * UNITS + kt + slot * 8;
      *(s16x8*)&Bh[phys] = *(const s16x8*)&Bgh[go];
      *(s16x8*)&Bl[phys] = *(const s16x8*)&Bgl[go];
    }
    __syncthreads();

    bf16x8 bh[2], bl[2];
#pragma unroll
    for (int n = 0; n < 2; ++n) {
      int R = n * 16 + lr;
      int phys = R * 32 + (((kg + (R >> 1)) & 3) << 3);
      bh[n] = *(const bf16x8*)&Bh[phys];
      bl[n] = *(const bf16x8*)&Bl[phys];
    }
#pragma unroll
    for (int m = 0; m < 2; ++m) {
      int R = w * 32 + m * 16 + lr;
      int phys = R * 32 + (((kg + (R >> 1)) & 3) << 3);
      bf16x8 ah = *(const bf16x8*)&Ah[phys];
      bf16x8 al = *(const bf16x8*)&Al[phys];
#pragma unroll
      for (int n = 0; n < 2; ++n) {
        acc[m][n] = __builtin_amdgcn_mfma_f32_16x16x32_bf16(ah, bh[n], acc[m][n], 0, 0, 0);
        acc[m][n] = __builtin_amdgcn_mfma_f32_16x16x32_bf16(ah, bl[n], acc[m][n], 0, 0, 0);
        acc[m][n] = __builtin_amdgcn_mfma_f32_16x16x32_bf16(al, bh[n], acc[m][n], 0, 0, 0);
      }
    }
  }
#pragma unroll
  for (int m = 0; m < 2; ++m)
#pragma unroll
    for (int n = 0; n < 2; ++n) {
      long gr0 = bm + w * 32 + m * 16 + kg * 4;
      int gc = n * 16 + lr;
#pragma unroll
      for (int r = 0; r < 4; ++r)
        coeff[(size_t)(gr0 + r) * 32 + gc] = acc[m][n][r];
    }
}

// ---------- gaussian head: 1 wave/row, 2 rows per 128-thread block ----------
// Packed-e parked in LDS (round-14: removes spills). Round-15 micro-opts:
// pass-1 pack via one v_perm (saves and/shr/or); sm accumulated from the
// SAME packed/truncated bits (consistent renorm -> round-10 absmax);
// pass-2 float2 vector fma (v_pk_fma_f32 dual-issue) + single
// v_cvt_pk_bf16_f32 for the two output stores. Closed-form softmax max via
// endpoint convexity; hw trans pipe; base-2: exp(0.5*d^2)==2^((d*s)^2).
__global__ __launch_bounds__(128) void gauss_kernel(
    const float* __restrict__ coeff, const float* __restrict__ fn_g,
    const float* __restrict__ fn_b, const float* __restrict__ wn_g,
    const float* __restrict__ wn_b, const float* __restrict__ freqs,
    unsigned short* __restrict__ amps)
{
  __shared__ u32x4 pkL[2][19][64];   // 38,912 B -> 4 blocks/CU (8 waves)
  const int wid = threadIdx.x >> 6;  // 0..1
  const int t = threadIdx.x & 63;
  const int b = blockIdx.x * 2 + wid;
  const float cv = coeff[(size_t)b * 32 + (t & 31)];
  const float L2E = 1.4426950408889634f;

  float c2[8], c3[8];
  float m2 = 0.f, m3 = 0.f;
#pragma unroll
  for (int g = 0; g < 8; ++g) {
    c2[g] = __shfl(cv, 4 * g + 2);
    c3[g] = __shfl(cv, 4 * g + 3);
    m2 += c2[g]; m3 += c3[g];
  }
  m2 *= 0.125f; m3 *= 0.125f;
  float v2 = 0.f, v3 = 0.f;
#pragma unroll
  for (int g = 0; g < 8; ++g) {
    float d2 = c2[g] - m2; v2 += d2 * d2;
    float d3 = c3[g] - m3; v3 += d3 * d3;
  }
  v2 *= 0.125f; v3 *= 0.125f;
  const float r2 = rsqrtf(v2 + 1e-5f), r3 = rsqrtf(v3 + 1e-5f);

  const float S2 = 0.8493218f;  // sqrt(0.5 * log2(e))
  const float fv0 = freqs[0], fvL = freqs[NF - 1];
  float aa[8], oo[8], mxm[8];
#pragma unroll
  for (int g = 0; g < 8; ++g) {
    float z3 = (c3[g] - m3) * r3 * fn_g[g] + fn_b[g];
    float sig = frcp(1.f + fexp2(-z3 * L2E));
    float cfg = frcp(1.f + sig * 608.f);
    float z2 = (c2[g] - m2) * r2 * wn_g[g] + wn_b[g];
    float x = 10.f * z2;
    float enx = fexp2(-fabsf(x) * L2E);
    float sp = (fmaxf(x, 0.f) + 0.6931471805599453f * flog2(1.f + enx)) * 0.1f;
    float iwg = cfg * frcp(fmaxf(sp, 1e-6f));
    aa[g] = iwg * S2;
    oo[g] = cfg * iwg * S2;
    float d0 = fmaf(fv0, aa[g], -oo[g]);
    float dL = fmaf(fvL, aa[g], -oo[g]);
    mxm[g] = fmaxf(d0 * d0, dL * dL);
  }

  float sm[8];
#pragma unroll
  for (int g = 0; g < 8; ++g) sm[g] = 0.f;

  // ---- single exponent pass: e -> v_perm pack -> LDS; sm from packed bits ----
#pragma unroll
  for (int i = 0; i < 19; ++i) {
    int f = t + 64 * i;
    float fv = freqs[min(f, NF - 1)];
    u32x4 pw;
#pragma unroll
    for (int j = 0; j < 4; ++j) {
      float d0 = fmaf(fv, aa[2 * j], -oo[2 * j]);
      float e0 = fexp2(fmaf(d0, d0, -mxm[2 * j]));
      float d1 = fmaf(fv, aa[2 * j + 1], -oo[2 * j + 1]);
      float e1 = fexp2(fmaf(d1, d1, -mxm[2 * j + 1]));
      if (i == 18 && t == 63) { e0 = 0.f; e1 = 0.f; }
      unsigned p = __builtin_amdgcn_perm(__builtin_bit_cast(unsigned, e1),
                                         __builtin_bit_cast(unsigned, e0),
                                         0x07060302u);  // [e1.hi16|e0.hi16]
      pw[j] = p;
      sm[2 * j]     += __builtin_bit_cast(float, p << 16);
      sm[2 * j + 1] += __builtin_bit_cast(float, p & 0xFFFF0000u);
    }
    pkL[wid][i][t] = pw;  // one ds_write_b128
  }

  f32x2 ws2[4], wc2[4];
#pragma unroll
  for (int g = 0; g < 8; ++g) {
#pragma unroll
    for (int m = 32; m >= 1; m >>= 1) sm[g] += __shfl_xor(sm[g], m);
    float inv = frcp(sm[g]);
    float wsn = __shfl(cv, 4 * g + 0) * inv;
    float wcn = __shfl(cv, 4 * g + 1) * inv;
    ws2[g >> 1][g & 1] = wsn;
    wc2[g >> 1][g & 1] = wcn;
  }

  // ---- accumulate (packed float2 fma) + store via v_cvt_pk_bf16_f32 ----
  size_t base = (size_t)b * KF;
#pragma unroll
  for (int i = 0; i < 19; ++i) {
    u32x4 pw = pkL[wid][i][t];  // one ds_read_b128
    f32x2 as2 = {0.f, 0.f}, ac2 = {0.f, 0.f};
#pragma unroll
    for (int j = 0; j < 4; ++j) {
      f32x2 e2;
      e2[0] = __builtin_bit_cast(float, pw[j] << 16);
      e2[1] = __builtin_bit_cast(float, pw[j] & 0xFFFF0000u);
      as2 += e2 * ws2[j];
      ac2 += e2 * wc2[j];
    }
    float as = as2[0] + as2[1];
    float ac = ac2[0] + ac2[1];
    int f = t + 64 * i;
    if (f < NF) {
      unsigned r;
      asm("v_cvt_pk_bf16_f32 %0, %1, %2" : "=v"(r) : "v"(as), "v"(ac));
      amps[base + f] = (unsigned short)(r & 0xFFFFu);
      amps[base + NF + f] = (unsigned short)(r >> 16);
    }
  }
  if (t == 0) {
    amps[base + 2430] = 0;
    amps[base + 2431] = 0;
  }
}

extern "C" void kernel_launch(void* const* d_in, const int* in_sizes, int n_in,
                              void* d_out, int out_size, void* d_ws, size_t ws_size,
                              hipStream_t stream) {
  (void)in_sizes; (void)n_in; (void)out_size; (void)ws_size;
  const float* x = (const float*)d_in[0];
  const float* fcw[4] = {(const float*)d_in[1], (const float*)d_in[3],
                         (const float*)d_in[5], (const float*)d_in[7]};
  const float* fcb[4] = {(const float*)d_in[2], (const float*)d_in[4],
                         (const float*)d_in[6], (const float*)d_in[8]};
  const float* theta_w = (const float*)d_in[9];
  const float* fn_g = (const float*)d_in[10];
  const float* fn_b = (const float*)d_in[11];
  const float* wn_g = (const float*)d_in[12];
  const float* wn_b = (const float*)d_in[13];
  const float* freqs = (const float*)d_in[14];
  const float* sb = (const float*)d_in[15];
  const float* sf = (const float*)d_in[16];
  float* out = (float*)d_out;

  char* p = (char*)d_ws;
  auto take = [&](size_t bytes) {
    char* r = p;
    p += (bytes + 255) & ~(size_t)255;
    return r;
  };
  unsigned short* h0h = (unsigned short*)take((size_t)BATCH * UNITS * 2);
  unsigned short* h0l = (unsigned short*)take((size_t)BATCH * UNITS * 2);
  unsigned short* h1h = (unsigned short*)take((size_t)BATCH * UNITS * 2);
  unsigned short* h1l = (unsigned short*)take((size_t)BATCH * UNITS * 2);
  unsigned short *wh[4], *wl[4];
  for (int l = 0; l < 4; ++l) {
    wh[l] = (unsigned short*)take((size_t)UNITS * UNITS * 2);
    wl[l] = (unsigned short*)take((size_t)UNITS * UNITS * 2);
  }
  unsigned short* twh = (unsigned short*)take((size_t)32 * UNITS * 2);
  unsigned short* twl = (unsigned short*)take((size_t)32 * UNITS * 2);
  float* coeff = (float*)take((size_t)BATCH * 32 * 4);
  unsigned short* st = (unsigned short*)take((size_t)640 * KF * 2);
  unsigned short* amps = (unsigned short*)take((size_t)BATCH * KF * 2);

  // prep: all fp32->bf16(hi,lo) splits in ONE launch
  SplitArgs sa;
  sa.seg[0] = {x,       h0h,   h0l,   (unsigned)(BATCH * UNITS / 4)};
  sa.seg[1] = {fcw[0],  wh[0], wl[0], (unsigned)(UNITS * UNITS / 4)};
  sa.seg[2] = {fcw[1],  wh[1], wl[1], (unsigned)(UNITS * UNITS / 4)};
  sa.seg[3] = {fcw[2],  wh[2], wl[2], (unsigned)(UNITS * UNITS / 4)};
  sa.seg[4] = {fcw[3],  wh[3], wl[3], (unsigned)(UNITS * UNITS / 4)};
  sa.seg[5] = {theta_w, twh,   twl,   (unsigned)(32 * UNITS / 4)};
  sa.total4 = (unsigned)(BATCH * UNITS / 4 + 4 * (UNITS * UNITS / 4) + 32 * UNITS / 4);
  split_all<<<2048, 256, 0, stream>>>(sa);
  st_prep<<<dim3(KF / 32, 640 / 32), dim3(32, 8), 0, stream>>>(sb, sf, st);

  // FC stack (split-bf16): x->h1->h0->h1->h0   (1-D grid, XCD-aware mapping)
  gemm_fc<4><<<4 * (BATCH / 128), 256, 0, stream>>>(
      h0h, h0l, wh[0], wl[0], fcb[0], h1h, h1l);
  gemm_fc<4><<<4 * (BATCH / 128), 256, 0, stream>>>(
      h1h, h1l, wh[1], wl[1], fcb[1], h0h, h0l);
  gemm_fc<4><<<4 * (BATCH / 128), 256, 0, stream>>>(
      h0h, h0l, wh[2], wl[2], fcb[2], h1h, h1l);
  gemm_fc<4><<<4 * (BATCH / 128), 256, 0, stream>>>(
      h1h, h1l, wh[3], wl[3], fcb[3], h0h, h0l);

  // theta projection
  coeff_gemm<<<BATCH / 128, 256, 0, stream>>>(h0h, h0l, twh, twl, coeff);

  // gaussian head -> amps (bf16, padded to 2432); 1 wave/row, 2 rows/block
  gauss_kernel<<<BATCH / 2, 128, 0, stream>>>(coeff, fn_g, fn_b, wn_g, wn_b, freqs, amps);

  // final GEMM -> backcast + forecast (wide tile: 128x320, 2 bn tiles)
  gemm_wide<<<2 * (BATCH / 128), 256, 0, stream>>>(amps, st, out);
}

// Round 16
// 506.027 us; speedup vs baseline: 1.0580x; 1.0154x over previous
//
#include <hip/hip_runtime.h>
#include <hip/hip_bf16.h>
#include <math.h>

#define BATCH 32768
#define UNITS 512
#define NF 1215      // number of freqs = 2L-1
#define KF 2432      // padded 2*NF
#define NOUT 608     // 512 + 96

typedef __bf16 bf16x8 __attribute__((ext_vector_type(8)));
typedef float f32x4 __attribute__((ext_vector_type(4)));
typedef float f32x2 __attribute__((ext_vector_type(2)));
typedef short s16x4 __attribute__((ext_vector_type(4)));
typedef short s16x8 __attribute__((ext_vector_type(8)));
typedef unsigned u32x4 __attribute__((ext_vector_type(4)));

__device__ __forceinline__ unsigned short f2b(float f) {
  unsigned u = __builtin_bit_cast(unsigned, f);
  u += 0x7fffu + ((u >> 16) & 1u);
  return (unsigned short)(u >> 16);
}
__device__ __forceinline__ float b2f(unsigned short h) {
  unsigned u = ((unsigned)h) << 16;
  return __builtin_bit_cast(float, u);
}

#if __has_builtin(__builtin_amdgcn_exp2f)
__device__ __forceinline__ float fexp2(float x) { return __builtin_amdgcn_exp2f(x); }
#else
__device__ __forceinline__ float fexp2(float x) { return exp2f(x); }
#endif
#if __has_builtin(__builtin_amdgcn_logf)
__device__ __forceinline__ float flog2(float x) { return __builtin_amdgcn_logf(x); }
#else
__device__ __forceinline__ float flog2(float x) { return log2f(x); }
#endif
#if __has_builtin(__builtin_amdgcn_rcpf)
__device__ __forceinline__ float frcp(float x) { return __builtin_amdgcn_rcpf(x); }
#else
__device__ __forceinline__ float frcp(float x) { return 1.f / x; }
#endif

// async global->LDS, 16B per lane; LDS dest = wave-uniform base + lane*16
__device__ __forceinline__ void gload16(const unsigned short* g, unsigned short* l) {
  __builtin_amdgcn_global_load_lds(
      (const __attribute__((address_space(1))) void*)g,
      (__attribute__((address_space(3))) void*)l, 16, 0, 0);
}

// counted vmcnt wait (N = allowed outstanding VMEM ops), literal-templated
template <int N> __device__ __forceinline__ void wait_vm() {
  if constexpr (N == 0)      asm volatile("s_waitcnt vmcnt(0)" ::: "memory");
  else if constexpr (N == 4) asm volatile("s_waitcnt vmcnt(4)" ::: "memory");
  else if constexpr (N == 5) asm volatile("s_waitcnt vmcnt(5)" ::: "memory");
  else                       asm volatile("s_waitcnt vmcnt(8)" ::: "memory");
}
__device__ __forceinline__ void barrier_raw() {
  asm volatile("" ::: "memory");
  __builtin_amdgcn_s_barrier();
  asm volatile("" ::: "memory");
}

// ---------- prep: split fp32 -> bf16 hi + bf16 lo, ALL tensors in one launch ----
struct SplitSeg { const float* src; unsigned short* hi; unsigned short* lo; unsigned n4; };
struct SplitArgs { SplitSeg seg[6]; unsigned total4; };

__global__ __launch_bounds__(256) void split_all(SplitArgs a)
{
  unsigned i = blockIdx.x * 256 + threadIdx.x;
  const unsigned stride = gridDim.x * 256;
  for (; i < a.total4; i += stride) {
    unsigned rem = i;
#pragma unroll
    for (int s = 0; s < 6; ++s) {
      if (rem < a.seg[s].n4) {
        f32x4 v = ((const f32x4*)a.seg[s].src)[rem];
        s16x4 h, l;
#pragma unroll
        for (int j = 0; j < 4; ++j) {
          unsigned short hb = f2b(v[j]);
          h[j] = (short)hb;
          l[j] = (short)f2b(v[j] - b2f(hb));
        }
        ((s16x4*)a.seg[s].hi)[rem] = h;
        ((s16x4*)a.seg[s].lo)[rem] = l;
        break;
      }
      rem -= a.seg[s].n4;
    }
  }
}

// ---------- prep: st[n][k] = S[k][n] as bf16, padded to [640][2432] ----------
__global__ __launch_bounds__(256) void st_prep(
    const float* __restrict__ sb, const float* __restrict__ sf,
    unsigned short* __restrict__ st)
{
  __shared__ float tile[32][33];
  int k0 = blockIdx.x * 32, n0 = blockIdx.y * 32;
  int tx = threadIdx.x, ty = threadIdx.y;
#pragma unroll
  for (int yy = 0; yy < 32; yy += 8) {
    int k = k0 + ty + yy, n = n0 + tx;
    float v = 0.f;
    if (k < 2430) {
      if (n < 512) v = sb[(size_t)k * 512 + n];
      else if (n < NOUT) v = sf[(size_t)k * 96 + (n - 512)];
    }
    tile[ty + yy][tx] = v;
  }
  __syncthreads();
#pragma unroll
  for (int yy = 0; yy < 32; yy += 8) {
    int n = n0 + ty + yy, k = k0 + tx;
    st[(size_t)n * KF + k] = f2b(tile[tx][ty + yy]);
  }
}

// ---------- FC GEMM: C[M][512] = A[M][512] * W[512][512]^T, split-bf16 ----------
// 128x128 tile, 4 waves, NBUF=2. Per iter: STAGE(next tile, other buf) ->
// vmcnt(8) -> barrier -> compute -> barrier. NO setprio (round-9 lesson).
template <int NBN>
__global__ __launch_bounds__(256) void gemm_fc(
    const unsigned short* __restrict__ Agh, const unsigned short* __restrict__ Agl,
    const unsigned short* __restrict__ Bgh, const unsigned short* __restrict__ Bgl,
    const float* __restrict__ bias,
    unsigned short* __restrict__ Chi, unsigned short* __restrict__ Clo)
{
  constexpr int NT = 512 / 32;
  __shared__ unsigned short Ah[2][128 * 32];
  __shared__ unsigned short Bh[2][128 * 32];
  __shared__ unsigned short Al[2][128 * 32];
  __shared__ unsigned short Bl[2][128 * 32];

  const int t = threadIdx.x;
  const int lane = t & 63;
  const int w = t >> 6;
  const int wr = w >> 1, wc = w & 1;

  // XCD-aware mapping (BATCH/128 = 256 bm panels, 32 per XCD)
  const int lin = blockIdx.x;
  const int xcd = lin & 7;
  const int sub = lin >> 3;
  const long bm = (long)(xcd * 32 + sub / NBN) * 128;
  const int bn = (sub % NBN) * 128;

  const int lr = lane & 15, kg = lane >> 4;

  // staging: wave w fills windows w and w+4 (16 rows x 32 cols = 1KB each);
  // lane l -> row base+(l>>2), chunk l&3; inverse read-swizzle on global src.
  const int Rw = lane >> 2;
  const int pch = lane & 3;
  const int R1 = w * 16 + Rw;
  const int R2 = (w + 4) * 16 + Rw;
  const int s1 = (pch - (R1 >> 1)) & 3;
  const int s2 = (pch - (R2 >> 1)) & 3;
  const size_t oA1 = (size_t)(bm + R1) * UNITS + s1 * 8;
  const size_t oA2 = (size_t)(bm + R2) * UNITS + s2 * 8;
  const size_t oB1 = (size_t)(bn + R1) * UNITS + s1 * 8;
  const size_t oB2 = (size_t)(bn + R2) * UNITS + s2 * 8;

  auto STAGE = [&](int buf, int kt) {
    gload16(Agh + oA1 + kt, &Ah[buf][w * 512]);
    gload16(Agh + oA2 + kt, &Ah[buf][(w + 4) * 512]);
    gload16(Bgh + oB1 + kt, &Bh[buf][w * 512]);
    gload16(Bgh + oB2 + kt, &Bh[buf][(w + 4) * 512]);
    gload16(Agl + oA1 + kt, &Al[buf][w * 512]);
    gload16(Agl + oA2 + kt, &Al[buf][(w + 4) * 512]);
    gload16(Bgl + oB1 + kt, &Bl[buf][w * 512]);
    gload16(Bgl + oB2 + kt, &Bl[buf][(w + 4) * 512]);
  };

  const f32x4 fzero = {0.f, 0.f, 0.f, 0.f};
  f32x4 acc[4][4];
#pragma unroll
  for (int m = 0; m < 4; ++m)
#pragma unroll
    for (int n = 0; n < 4; ++n) acc[m][n] = fzero;

  STAGE(0, 0);
  int cur = 0;
  for (int it = 0; it < NT; ++it) {
    if (it + 1 < NT) { STAGE(cur ^ 1, (it + 1) * 32); wait_vm<8>(); }
    else wait_vm<0>();
    barrier_raw();  // stage(it) visible to all waves

    bf16x8 bhf[4], blf[4];
#pragma unroll
    for (int n = 0; n < 4; ++n) {
      int R = wc * 64 + n * 16 + lr;
      int phys = R * 32 + (((kg + (R >> 1)) & 3) << 3);
      bhf[n] = *(const bf16x8*)&Bh[cur][phys];
      blf[n] = *(const bf16x8*)&Bl[cur][phys];
    }
#pragma unroll
    for (int m = 0; m < 4; ++m) {
      int R = wr * 64 + m * 16 + lr;
      int phys = R * 32 + (((kg + (R >> 1)) & 3) << 3);
      bf16x8 ahf = *(const bf16x8*)&Ah[cur][phys];
      bf16x8 alf = *(const bf16x8*)&Al[cur][phys];
#pragma unroll
      for (int n = 0; n < 4; ++n) {
        acc[m][n] = __builtin_amdgcn_mfma_f32_16x16x32_bf16(ahf, bhf[n], acc[m][n], 0, 0, 0);
        acc[m][n] = __builtin_amdgcn_mfma_f32_16x16x32_bf16(ahf, blf[n], acc[m][n], 0, 0, 0);
        acc[m][n] = __builtin_amdgcn_mfma_f32_16x16x32_bf16(alf, bhf[n], acc[m][n], 0, 0, 0);
      }
    }
    barrier_raw();  // reads of buf `cur` done before next iter re-stages it
    cur ^= 1;
  }

  // epilogue: C/D layout col=lane&15, row=(lane>>4)*4+reg
#pragma unroll
  for (int m = 0; m < 4; ++m) {
#pragma unroll
    for (int n = 0; n < 4; ++n) {
      long gr0 = bm + wr * 64 + m * 16 + kg * 4;
      int gc = bn + wc * 64 + n * 16 + lr;
      float bv = bias[gc];
#pragma unroll
      for (int r = 0; r < 4; ++r) {
        float o = fmaxf(acc[m][n][r] + bv, 0.f);
        unsigned short h = f2b(o);
        size_t off = (size_t)(gr0 + r) * UNITS + gc;
        Chi[off] = h;
        Clo[off] = f2b(o - b2f(h));
      }
    }
  }
}

// ---------- final GEMM: out[M][608] = amps[M][KF] * st[640][KF]^T, plain bf16 ----
// Round 16: BN 320->160 (4 bn tiles). LDS 36KB/block -> 4 blocks/CU
// (144KB/CU), grid = 1024 = exactly 4/CU: doubled block-level concurrency
// so one block's barrier/latency wait hides under another's MFMA (m114
// implicit overlap). Wave tile 64x80, acc[4][5], 20 MFMA/period. Staging:
// 18 windows (8 A + 10 B); waves 0-1 carry 5 loads/stage, waves 2-3 carry 4
// -> per-wave counted vmcnt. 4 bn-blocks of one panel stay on one XCD.
__global__ __launch_bounds__(256, 4) void gemm_wide(
    const unsigned short* __restrict__ Ag, const unsigned short* __restrict__ Bg,
    float* __restrict__ outF)
{
  constexpr int NT = KF / 32;  // 76
  __shared__ unsigned short Ah[2][128 * 32];   // 16KB
  __shared__ unsigned short Bh[2][160 * 32];   // 20KB

  const int t = threadIdx.x;
  const int lane = t & 63;
  const int w = t >> 6;
  const int wr = w >> 1, wc = w & 1;

  // XCD mapping: 256 bm panels x 4 bn tiles; 32 panels per XCD
  const int lin = blockIdx.x;
  const int xcd = lin & 7;
  const int sub = lin >> 3;           // 0..127
  const long bm = (long)(xcd * 32 + (sub >> 2)) * 128;
  const int bn = (sub & 3) * 160;

  const int lr = lane & 15, kg = lane >> 4;
  const int Rl = lane >> 2, pch = lane & 3;

  // A: 8 windows; wave w stages windows w, w+4
  const int RA1 = w * 16 + Rl, RA2 = (w + 4) * 16 + Rl;
  const int sA1 = (pch - (RA1 >> 1)) & 3, sA2 = (pch - (RA2 >> 1)) & 3;
  const size_t oA1 = (size_t)(bm + RA1) * KF + sA1 * 8;
  const size_t oA2 = (size_t)(bm + RA2) * KF + sA2 * 8;
  // B: 10 windows; waves 0-1 take 3 (0..2 / 3..5), waves 2-3 take 2 (6..7 / 8..9)
  const int nb = (w < 2) ? 3 : 2;
  const int b0 = (w < 2) ? w * 3 : 6 + (w - 2) * 2;
  size_t oB[3];
#pragma unroll
  for (int j = 0; j < 3; ++j) {
    int q = b0 + ((j < nb) ? j : 0);
    int R = q * 16 + Rl;
    int s = (pch - (R >> 1)) & 3;
    oB[j] = (size_t)(bn + R) * KF + s * 8;
  }

  auto STAGE = [&](int buf, int kt) {
    gload16(Ag + oA1 + kt, &Ah[buf][w * 512]);
    gload16(Ag + oA2 + kt, &Ah[buf][(w + 4) * 512]);
#pragma unroll
    for (int j = 0; j < 3; ++j)
      if (j < nb) gload16(Bg + oB[j] + kt, &Bh[buf][(b0 + j) * 512]);
  };

  const f32x4 fzero = {0.f, 0.f, 0.f, 0.f};
  f32x4 acc[4][5];
#pragma unroll
  for (int m = 0; m < 4; ++m)
#pragma unroll
    for (int n = 0; n < 5; ++n) acc[m][n] = fzero;

  STAGE(0, 0);
  int cur = 0;
  for (int it = 0; it < NT; ++it) {
    if (it + 1 < NT) {
      STAGE(cur ^ 1, (it + 1) * 32);
      if (w < 2) wait_vm<5>(); else wait_vm<4>();
    } else wait_vm<0>();
    barrier_raw();

    bf16x8 af[4];
#pragma unroll
    for (int m = 0; m < 4; ++m) {
      int R = wr * 64 + m * 16 + lr;
      af[m] = *(const bf16x8*)&Ah[cur][R * 32 + (((kg + (R >> 1)) & 3) << 3)];
    }
#pragma unroll
    for (int n = 0; n < 5; ++n) {
      int R = wc * 80 + n * 16 + lr;
      bf16x8 bf = *(const bf16x8*)&Bh[cur][R * 32 + (((kg + (R >> 1)) & 3) << 3)];
#pragma unroll
      for (int m = 0; m < 4; ++m)
        acc[m][n] = __builtin_amdgcn_mfma_f32_16x16x32_bf16(af[m], bf, acc[m][n], 0, 0, 0);
    }
    barrier_raw();
    cur ^= 1;
  }

  // epilogue
#pragma unroll
  for (int m = 0; m < 4; ++m) {
#pragma unroll
    for (int n = 0; n < 5; ++n) {
      long gr0 = bm + wr * 64 + m * 16 + kg * 4;
      int gc = bn + wc * 80 + n * 16 + lr;
      if (gc < NOUT) {
#pragma unroll
        for (int r = 0; r < 4; ++r) {
          float o = acc[m][n][r];
          long row = gr0 + r;
          if (gc < 512) outF[row * 512 + gc] = o;
          else outF[(size_t)BATCH * 512 + row * 96 + (gc - 512)] = o;
        }
      }
    }
  }
}

// ---------- theta projection: coeff[M][32] = h3[M][512] * theta_w[32][512]^T, split-bf16 ----------
__global__ __launch_bounds__(256) void coeff_gemm(
    const unsigned short* __restrict__ Agh, const unsigned short* __restrict__ Agl,
    const unsigned short* __restrict__ Bgh, const unsigned short* __restrict__ Bgl,
    float* __restrict__ coeff)
{
  __shared__ unsigned short Ah[128 * 32];
  __shared__ unsigned short Al[128 * 32];
  __shared__ unsigned short Bh[32 * 32];
  __shared__ unsigned short Bl[32 * 32];

  const int t = threadIdx.x;
  const int lane = t & 63;
  const int w = t >> 6;
  const long bm = (long)blockIdx.x * 128;
  const int lr = lane & 15, kg = lane >> 4;

  const f32x4 fzero = {0.f, 0.f, 0.f, 0.f};
  f32x4 acc[2][2];
#pragma unroll
  for (int m = 0; m < 2; ++m)
#pragma unroll
    for (int n = 0; n < 2; ++n) acc[m][n] = fzero;

  for (int kt = 0; kt < 512; kt += 32) {
    __syncthreads();
#pragma unroll
    for (int p = 0; p < 2; ++p) {
      int c = t + 256 * p;
      int row = c >> 2, slot = c & 3;
      int phys = row * 32 + (((slot + (row >> 1)) & 3) << 3);
      size_t go = (size_t)(bm + row) * UNITS + kt + slot * 8;
      *(s16x8*)&Ah[phys] = *(const s16x8*)&Agh[go];
      *(s16x8*)&Al[phys] = *(const s16x8*)&Agl[go];
    }
    if (t < 128) {
      int row = t >> 2, slot = t & 3;
      int phys = row * 32 + (((slot + (row >> 1)) & 3) << 3);
      size_t go = (size_t)row * UNITS + kt + slot * 8;
      *(s16x8*)&Bh[phys] = *(const s16x8*)&Bgh[go];
      *(s16x8*)&Bl[phys] = *(const s16x8*)&Bgl[go];
    }
    __syncthreads();

    bf16x8 bh[2], bl[2];
#pragma unroll
    for (int n = 0; n < 2; ++n) {
      int R = n * 16 + lr;
      int phys = R * 32 + (((kg + (R >> 1)) & 3) << 3);
      bh[n] = *(const bf16x8*)&Bh[phys];
      bl[n] = *(const bf16x8*)&Bl[phys];
    }
#pragma unroll
    for (int m = 0; m < 2; ++m) {
      int R = w * 32 + m * 16 + lr;
      int phys = R * 32 + (((kg + (R >> 1)) & 3) << 3);
      bf16x8 ah = *(const bf16x8*)&Ah[phys];
      bf16x8 al = *(const bf16x8*)&Al[phys];
#pragma unroll
      for (int n = 0; n < 2; ++n) {
        acc[m][n] = __builtin_amdgcn_mfma_f32_16x16x32_bf16(ah, bh[n], acc[m][n], 0, 0, 0);
        acc[m][n] = __builtin_amdgcn_mfma_f32_16x16x32_bf16(ah, bl[n], acc[m][n], 0, 0, 0);
        acc[m][n] = __builtin_amdgcn_mfma_f32_16x16x32_bf16(al, bh[n], acc[m][n], 0, 0, 0);
      }
    }
  }
#pragma unroll
  for (int m = 0; m < 2; ++m)
#pragma unroll
    for (int n = 0; n < 2; ++n) {
      long gr0 = bm + w * 32 + m * 16 + kg * 4;
      int gc = n * 16 + lr;
#pragma unroll
      for (int r = 0; r < 4; ++r)
        coeff[(size_t)(gr0 + r) * 32 + gc] = acc[m][n][r];
    }
}

// ---------- gaussian head: 1 wave/row, 2 rows per 128-thread block ----------
// Packed-e parked in LDS (removes spills). Round-16: pass-1 math in f32x2
// (v_pk_fma_f32 for d and arg; packed sm accumulate) - identical IEEE fma
// per component -> absmax preserved. Pass-2 float2 fma + v_cvt_pk_bf16_f32
// store. sm from the SAME packed/truncated bits (consistent renorm).
// Closed-form softmax max via endpoint convexity; hw trans pipe; base-2.
__global__ __launch_bounds__(128) void gauss_kernel(
    const float* __restrict__ coeff, const float* __restrict__ fn_g,
    const float* __restrict__ fn_b, const float* __restrict__ wn_g,
    const float* __restrict__ wn_b, const float* __restrict__ freqs,
    unsigned short* __restrict__ amps)
{
  __shared__ u32x4 pkL[2][19][64];   // 38,912 B -> 4 blocks/CU (8 waves)
  const int wid = threadIdx.x >> 6;  // 0..1
  const int t = threadIdx.x & 63;
  const int b = blockIdx.x * 2 + wid;
  const float cv = coeff[(size_t)b * 32 + (t & 31)];
  const float L2E = 1.4426950408889634f;

  float c2[8], c3[8];
  float m2 = 0.f, m3 = 0.f;
#pragma unroll
  for (int g = 0; g < 8; ++g) {
    c2[g] = __shfl(cv, 4 * g + 2);
    c3[g] = __shfl(cv, 4 * g + 3);
    m2 += c2[g]; m3 += c3[g];
  }
  m2 *= 0.125f; m3 *= 0.125f;
  float v2 = 0.f, v3 = 0.f;
#pragma unroll
  for (int g = 0; g < 8; ++g) {
    float d2 = c2[g] - m2; v2 += d2 * d2;
    float d3 = c3[g] - m3; v3 += d3 * d3;
  }
  v2 *= 0.125f; v3 *= 0.125f;
  const float r2 = rsqrtf(v2 + 1e-5f), r3 = rsqrtf(v3 + 1e-5f);

  const float S2 = 0.8493218f;  // sqrt(0.5 * log2(e))
  const float fv0 = freqs[0], fvL = freqs[NF - 1];
  f32x2 aa2[4], oo2[4], mx2[4];
#pragma unroll
  for (int g = 0; g < 8; ++g) {
    float z3 = (c3[g] - m3) * r3 * fn_g[g] + fn_b[g];
    float sig = frcp(1.f + fexp2(-z3 * L2E));
    float cfg = frcp(1.f + sig * 608.f);
    float z2 = (c2[g] - m2) * r2 * wn_g[g] + wn_b[g];
    float x = 10.f * z2;
    float enx = fexp2(-fabsf(x) * L2E);
    float sp = (fmaxf(x, 0.f) + 0.6931471805599453f * flog2(1.f + enx)) * 0.1f;
    float iwg = cfg * frcp(fmaxf(sp, 1e-6f));
    float aag = iwg * S2;
    float oog = cfg * iwg * S2;
    float d0 = fmaf(fv0, aag, -oog);
    float dL = fmaf(fvL, aag, -oog);
    aa2[g >> 1][g & 1] = aag;
    oo2[g >> 1][g & 1] = oog;
    mx2[g >> 1][g & 1] = fmaxf(d0 * d0, dL * dL);
  }

  f32x2 sm2[4];
#pragma unroll
  for (int j = 0; j < 4; ++j) sm2[j] = (f32x2){0.f, 0.f};

  // ---- single exponent pass: packed d/arg (v_pk_fma), scalar exp2,
  //      v_perm pack -> LDS; sm from packed/truncated bits ----
#pragma unroll
  for (int i = 0; i < 19; ++i) {
    int f = t + 64 * i;
    float fv = freqs[min(f, NF - 1)];
    f32x2 fv2 = {fv, fv};
    u32x4 pw;
#pragma unroll
    for (int j = 0; j < 4; ++j) {
      f32x2 d2v = fv2 * aa2[j] - oo2[j];
      f32x2 arg = d2v * d2v - mx2[j];
      float e0 = fexp2(arg[0]);
      float e1 = fexp2(arg[1]);
      if (i == 18 && t == 63) { e0 = 0.f; e1 = 0.f; }
      unsigned p = __builtin_amdgcn_perm(__builtin_bit_cast(unsigned, e1),
                                         __builtin_bit_cast(unsigned, e0),
                                         0x07060302u);  // [e1.hi16|e0.hi16]
      pw[j] = p;
      f32x2 e2;
      e2[0] = __builtin_bit_cast(float, p << 16);
      e2[1] = __builtin_bit_cast(float, p & 0xFFFF0000u);
      sm2[j] += e2;
    }
    pkL[wid][i][t] = pw;  // one ds_write_b128
  }

  f32x2 ws2[4], wc2[4];
#pragma unroll
  for (int j = 0; j < 4; ++j) {
    float s0 = sm2[j][0], s1 = sm2[j][1];
#pragma unroll
    for (int m = 32; m >= 1; m >>= 1) {
      s0 += __shfl_xor(s0, m);
      s1 += __shfl_xor(s1, m);
    }
    float inv0 = frcp(s0), inv1 = frcp(s1);
    ws2[j][0] = __shfl(cv, 8 * j + 0) * inv0;
    ws2[j][1] = __shfl(cv, 8 * j + 4) * inv1;
    wc2[j][0] = __shfl(cv, 8 * j + 1) * inv0;
    wc2[j][1] = __shfl(cv, 8 * j + 5) * inv1;
  }

  // ---- accumulate (packed float2 fma) + store via v_cvt_pk_bf16_f32 ----
  size_t base = (size_t)b * KF;
#pragma unroll
  for (int i = 0; i < 19; ++i) {
    u32x4 pw = pkL[wid][i][t];  // one ds_read_b128
    f32x2 as2 = {0.f, 0.f}, ac2 = {0.f, 0.f};
#pragma unroll
    for (int j = 0; j < 4; ++j) {
      f32x2 e2;
      e2[0] = __builtin_bit_cast(float, pw[j] << 16);
      e2[1] = __builtin_bit_cast(float, pw[j] & 0xFFFF0000u);
      as2 += e2 * ws2[j];
      ac2 += e2 * wc2[j];
    }
    float as = as2[0] + as2[1];
    float ac = ac2[0] + ac2[1];
    int f = t + 64 * i;
    if (f < NF) {
      unsigned r;
      asm("v_cvt_pk_bf16_f32 %0, %1, %2" : "=v"(r) : "v"(as), "v"(ac));
      amps[base + f] = (unsigned short)(r & 0xFFFFu);
      amps[base + NF + f] = (unsigned short)(r >> 16);
    }
  }
  if (t == 0) {
    amps[base + 2430] = 0;
    amps[base + 2431] = 0;
  }
}

extern "C" void kernel_launch(void* const* d_in, const int* in_sizes, int n_in,
                              void* d_out, int out_size, void* d_ws, size_t ws_size,
                              hipStream_t stream) {
  (void)in_sizes; (void)n_in; (void)out_size; (void)ws_size;
  const float* x = (const float*)d_in[0];
  const float* fcw[4] = {(const float*)d_in[1], (const float*)d_in[3],
                         (const float*)d_in[5], (const float*)d_in[7]};
  const float* fcb[4] = {(const float*)d_in[2], (const float*)d_in[4],
                         (const float*)d_in[6], (const float*)d_in[8]};
  const float* theta_w = (const float*)d_in[9];
  const float* fn_g = (const float*)d_in[10];
  const float* fn_b = (const float*)d_in[11];
  const float* wn_g = (const float*)d_in[12];
  const float* wn_b = (const float*)d_in[13];
  const float* freqs = (const float*)d_in[14];
  const float* sb = (const float*)d_in[15];
  const float* sf = (const float*)d_in[16];
  float* out = (float*)d_out;

  char* p = (char*)d_ws;
  auto take = [&](size_t bytes) {
    char* r = p;
    p += (bytes + 255) & ~(size_t)255;
    return r;
  };
  unsigned short* h0h = (unsigned short*)take((size_t)BATCH * UNITS * 2);
  unsigned short* h0l = (unsigned short*)take((size_t)BATCH * UNITS * 2);
  unsigned short* h1h = (unsigned short*)take((size_t)BATCH * UNITS * 2);
  unsigned short* h1l = (unsigned short*)take((size_t)BATCH * UNITS * 2);
  unsigned short *wh[4], *wl[4];
  for (int l = 0; l < 4; ++l) {
    wh[l] = (unsigned short*)take((size_t)UNITS * UNITS * 2);
    wl[l] = (unsigned short*)take((size_t)UNITS * UNITS * 2);
  }
  unsigned short* twh = (unsigned short*)take((size_t)32 * UNITS * 2);
  unsigned short* twl = (unsigned short*)take((size_t)32 * UNITS * 2);
  float* coeff = (float*)take((size_t)BATCH * 32 * 4);
  unsigned short* st = (unsigned short*)take((size_t)640 * KF * 2);
  unsigned short* amps = (unsigned short*)take((size_t)BATCH * KF * 2);

  // prep: all fp32->bf16(hi,lo) splits in ONE launch
  SplitArgs sa;
  sa.seg[0] = {x,       h0h,   h0l,   (unsigned)(BATCH * UNITS / 4)};
  sa.seg[1] = {fcw[0],  wh[0], wl[0], (unsigned)(UNITS * UNITS / 4)};
  sa.seg[2] = {fcw[1],  wh[1], wl[1], (unsigned)(UNITS * UNITS / 4)};
  sa.seg[3] = {fcw[2],  wh[2], wl[2], (unsigned)(UNITS * UNITS / 4)};
  sa.seg[4] = {fcw[3],  wh[3], wl[3], (unsigned)(UNITS * UNITS / 4)};
  sa.seg[5] = {theta_w, twh,   twl,   (unsigned)(32 * UNITS / 4)};
  sa.total4 = (unsigned)(BATCH * UNITS / 4 + 4 * (UNITS * UNITS / 4) + 32 * UNITS / 4);
  split_all<<<2048, 256, 0, stream>>>(sa);
  st_prep<<<dim3(KF / 32, 640 / 32), dim3(32, 8), 0, stream>>>(sb, sf, st);

  // FC stack (split-bf16): x->h1->h0->h1->h0   (1-D grid, XCD-aware mapping)
  gemm_fc<4><<<4 * (BATCH / 128), 256, 0, stream>>>(
      h0h, h0l, wh[0], wl[0], fcb[0], h1h, h1l);
  gemm_fc<4><<<4 * (BATCH / 128), 256, 0, stream>>>(
      h1h, h1l, wh[1], wl[1], fcb[1], h0h, h0l);
  gemm_fc<4><<<4 * (BATCH / 128), 256, 0, stream>>>(
      h0h, h0l, wh[2], wl[2], fcb[2], h1h, h1l);
  gemm_fc<4><<<4 * (BATCH / 128), 256, 0, stream>>>(
      h1h, h1l, wh[3], wl[3], fcb[3], h0h, h0l);

  // theta projection
  coeff_gemm<<<BATCH / 128, 256, 0, stream>>>(h0h, h0l, twh, twl, coeff);

  // gaussian head -> amps (bf16, padded to 2432); 1 wave/row, 2 rows/block
  gauss_kernel<<<BATCH / 2, 128, 0, stream>>>(coeff, fn_g, fn_b, wn_g, wn_b, freqs, amps);

  // final GEMM -> backcast + forecast (128x160 tile, 4 bn tiles, 4 blocks/CU)
  gemm_wide<<<4 * (BATCH / 128), 256, 0, stream>>>(amps, st, out);
}

// Round 17
// 491.681 us; speedup vs baseline: 1.0888x; 1.0292x over previous
//
#include <hip/hip_runtime.h>
#include <hip/hip_bf16.h>
#include <math.h>

#define BATCH 32768
#define UNITS 512
#define NF 1215      // number of freqs = 2L-1
#define KF 2432      // padded 2*NF
#define NOUT 608     // 512 + 96

typedef __bf16 bf16x8 __attribute__((ext_vector_type(8)));
typedef float f32x4 __attribute__((ext_vector_type(4)));
typedef float f32x2 __attribute__((ext_vector_type(2)));
typedef short s16x4 __attribute__((ext_vector_type(4)));
typedef short s16x8 __attribute__((ext_vector_type(8)));
typedef unsigned u32x4 __attribute__((ext_vector_type(4)));

__device__ __forceinline__ unsigned short f2b(float f) {
  unsigned u = __builtin_bit_cast(unsigned, f);
  u += 0x7fffu + ((u >> 16) & 1u);
  return (unsigned short)(u >> 16);
}
__device__ __forceinline__ float b2f(unsigned short h) {
  unsigned u = ((unsigned)h) << 16;
  return __builtin_bit_cast(float, u);
}

#if __has_builtin(__builtin_amdgcn_exp2f)
__device__ __forceinline__ float fexp2(float x) { return __builtin_amdgcn_exp2f(x); }
#else
__device__ __forceinline__ float fexp2(float x) { return exp2f(x); }
#endif
#if __has_builtin(__builtin_amdgcn_logf)
__device__ __forceinline__ float flog2(float x) { return __builtin_amdgcn_logf(x); }
#else
__device__ __forceinline__ float flog2(float x) { return log2f(x); }
#endif
#if __has_builtin(__builtin_amdgcn_rcpf)
__device__ __forceinline__ float frcp(float x) { return __builtin_amdgcn_rcpf(x); }
#else
__device__ __forceinline__ float frcp(float x) { return 1.f / x; }
#endif

// async global->LDS, 16B per lane; LDS dest = wave-uniform base + lane*16
__device__ __forceinline__ void gload16(const unsigned short* g, unsigned short* l) {
  __builtin_amdgcn_global_load_lds(
      (const __attribute__((address_space(1))) void*)g,
      (__attribute__((address_space(3))) void*)l, 16, 0, 0);
}

// counted vmcnt wait (N = allowed outstanding VMEM ops), literal-templated
template <int N> __device__ __forceinline__ void wait_vm() {
  if constexpr (N == 0)      asm volatile("s_waitcnt vmcnt(0)" ::: "memory");
  else if constexpr (N == 7) asm volatile("s_waitcnt vmcnt(7)" ::: "memory");
  else                       asm volatile("s_waitcnt vmcnt(8)" ::: "memory");
}
__device__ __forceinline__ void barrier_raw() {
  asm volatile("" ::: "memory");
  __builtin_amdgcn_s_barrier();
  asm volatile("" ::: "memory");
}

// ---------- prep: split fp32 -> bf16 hi + bf16 lo, ALL tensors in one launch ----
struct SplitSeg { const float* src; unsigned short* hi; unsigned short* lo; unsigned n4; };
struct SplitArgs { SplitSeg seg[6]; unsigned total4; };

__global__ __launch_bounds__(256) void split_all(SplitArgs a)
{
  unsigned i = blockIdx.x * 256 + threadIdx.x;
  const unsigned stride = gridDim.x * 256;
  for (; i < a.total4; i += stride) {
    unsigned rem = i;
#pragma unroll
    for (int s = 0; s < 6; ++s) {
      if (rem < a.seg[s].n4) {
        f32x4 v = ((const f32x4*)a.seg[s].src)[rem];
        s16x4 h, l;
#pragma unroll
        for (int j = 0; j < 4; ++j) {
          unsigned short hb = f2b(v[j]);
          h[j] = (short)hb;
          l[j] = (short)f2b(v[j] - b2f(hb));
        }
        ((s16x4*)a.seg[s].hi)[rem] = h;
        ((s16x4*)a.seg[s].lo)[rem] = l;
        break;
      }
      rem -= a.seg[s].n4;
    }
  }
}

// ---------- prep: st[n][k] = S[k][n] as bf16, padded to [640][2432] ----------
__global__ __launch_bounds__(256) void st_prep(
    const float* __restrict__ sb, const float* __restrict__ sf,
    unsigned short* __restrict__ st)
{
  __shared__ float tile[32][33];
  int k0 = blockIdx.x * 32, n0 = blockIdx.y * 32;
  int tx = threadIdx.x, ty = threadIdx.y;
#pragma unroll
  for (int yy = 0; yy < 32; yy += 8) {
    int k = k0 + ty + yy, n = n0 + tx;
    float v = 0.f;
    if (k < 2430) {
      if (n < 512) v = sb[(size_t)k * 512 + n];
      else if (n < NOUT) v = sf[(size_t)k * 96 + (n - 512)];
    }
    tile[ty + yy][tx] = v;
  }
  __syncthreads();
#pragma unroll
  for (int yy = 0; yy < 32; yy += 8) {
    int n = n0 + ty + yy, k = k0 + tx;
    st[(size_t)n * KF + k] = f2b(tile[tx][ty + yy]);
  }
}

// ---------- FC GEMM: C[M][512] = A[M][512] * W[512][512]^T, split-bf16 ----------
// 128x128 tile, 4 waves, NBUF=2. Per iter: STAGE(next tile, other buf) ->
// vmcnt(8) -> barrier -> compute -> barrier. NO setprio (round-9 lesson).
template <int NBN>
__global__ __launch_bounds__(256) void gemm_fc(
    const unsigned short* __restrict__ Agh, const unsigned short* __restrict__ Agl,
    const unsigned short* __restrict__ Bgh, const unsigned short* __restrict__ Bgl,
    const float* __restrict__ bias,
    unsigned short* __restrict__ Chi, unsigned short* __restrict__ Clo)
{
  constexpr int NT = 512 / 32;
  __shared__ unsigned short Ah[2][128 * 32];
  __shared__ unsigned short Bh[2][128 * 32];
  __shared__ unsigned short Al[2][128 * 32];
  __shared__ unsigned short Bl[2][128 * 32];

  const int t = threadIdx.x;
  const int lane = t & 63;
  const int w = t >> 6;
  const int wr = w >> 1, wc = w & 1;

  // XCD-aware mapping (BATCH/128 = 256 bm panels, 32 per XCD)
  const int lin = blockIdx.x;
  const int xcd = lin & 7;
  const int sub = lin >> 3;
  const long bm = (long)(xcd * 32 + sub / NBN) * 128;
  const int bn = (sub % NBN) * 128;

  const int lr = lane & 15, kg = lane >> 4;

  // staging: wave w fills windows w and w+4 (16 rows x 32 cols = 1KB each);
  // lane l -> row base+(l>>2), chunk l&3; inverse read-swizzle on global src.
  const int Rw = lane >> 2;
  const int pch = lane & 3;
  const int R1 = w * 16 + Rw;
  const int R2 = (w + 4) * 16 + Rw;
  const int s1 = (pch - (R1 >> 1)) & 3;
  const int s2 = (pch - (R2 >> 1)) & 3;
  const size_t oA1 = (size_t)(bm + R1) * UNITS + s1 * 8;
  const size_t oA2 = (size_t)(bm + R2) * UNITS + s2 * 8;
  const size_t oB1 = (size_t)(bn + R1) * UNITS + s1 * 8;
  const size_t oB2 = (size_t)(bn + R2) * UNITS + s2 * 8;

  auto STAGE = [&](int buf, int kt) {
    gload16(Agh + oA1 + kt, &Ah[buf][w * 512]);
    gload16(Agh + oA2 + kt, &Ah[buf][(w + 4) * 512]);
    gload16(Bgh + oB1 + kt, &Bh[buf][w * 512]);
    gload16(Bgh + oB2 + kt, &Bh[buf][(w + 4) * 512]);
    gload16(Agl + oA1 + kt, &Al[buf][w * 512]);
    gload16(Agl + oA2 + kt, &Al[buf][(w + 4) * 512]);
    gload16(Bgl + oB1 + kt, &Bl[buf][w * 512]);
    gload16(Bgl + oB2 + kt, &Bl[buf][(w + 4) * 512]);
  };

  const f32x4 fzero = {0.f, 0.f, 0.f, 0.f};
  f32x4 acc[4][4];
#pragma unroll
  for (int m = 0; m < 4; ++m)
#pragma unroll
    for (int n = 0; n < 4; ++n) acc[m][n] = fzero;

  STAGE(0, 0);
  int cur = 0;
  for (int it = 0; it < NT; ++it) {
    if (it + 1 < NT) { STAGE(cur ^ 1, (it + 1) * 32); wait_vm<8>(); }
    else wait_vm<0>();
    barrier_raw();  // stage(it) visible to all waves

    bf16x8 bhf[4], blf[4];
#pragma unroll
    for (int n = 0; n < 4; ++n) {
      int R = wc * 64 + n * 16 + lr;
      int phys = R * 32 + (((kg + (R >> 1)) & 3) << 3);
      bhf[n] = *(const bf16x8*)&Bh[cur][phys];
      blf[n] = *(const bf16x8*)&Bl[cur][phys];
    }
#pragma unroll
    for (int m = 0; m < 4; ++m) {
      int R = wr * 64 + m * 16 + lr;
      int phys = R * 32 + (((kg + (R >> 1)) & 3) << 3);
      bf16x8 ahf = *(const bf16x8*)&Ah[cur][phys];
      bf16x8 alf = *(const bf16x8*)&Al[cur][phys];
#pragma unroll
      for (int n = 0; n < 4; ++n) {
        acc[m][n] = __builtin_amdgcn_mfma_f32_16x16x32_bf16(ahf, bhf[n], acc[m][n], 0, 0, 0);
        acc[m][n] = __builtin_amdgcn_mfma_f32_16x16x32_bf16(ahf, blf[n], acc[m][n], 0, 0, 0);
        acc[m][n] = __builtin_amdgcn_mfma_f32_16x16x32_bf16(alf, bhf[n], acc[m][n], 0, 0, 0);
      }
    }
    barrier_raw();  // reads of buf `cur` done before next iter re-stages it
    cur ^= 1;
  }

  // epilogue: C/D layout col=lane&15, row=(lane>>4)*4+reg
#pragma unroll
  for (int m = 0; m < 4; ++m) {
#pragma unroll
    for (int n = 0; n < 4; ++n) {
      long gr0 = bm + wr * 64 + m * 16 + kg * 4;
      int gc = bn + wc * 64 + n * 16 + lr;
      float bv = bias[gc];
#pragma unroll
      for (int r = 0; r < 4; ++r) {
        float o = fmaxf(acc[m][n][r] + bv, 0.f);
        unsigned short h = f2b(o);
        size_t off = (size_t)(gr0 + r) * UNITS + gc;
        Chi[off] = h;
        Clo[off] = f2b(o - b2f(h));
      }
    }
  }
}

// ---------- final GEMM: out[M][608] = amps[M][KF] * st[640][KF]^T, plain bf16 ----
// WIDE tile: BM=128, BN=320, 4 waves, wave = 64x160, 40 MFMA/period.
// Uniform NBUF=2 staged A+B. LDS 56KB -> 2 blocks/CU; grid = 512 = exactly
// 2/CU. launch_bounds(256,2) pins regalloc. PROVEN 125us (rounds 10/15);
// BN=160/4-blocks (r16), split-depth (r11), A-from-global (r12) all lost.
__global__ __launch_bounds__(256, 2) void gemm_wide(
    const unsigned short* __restrict__ Ag, const unsigned short* __restrict__ Bg,
    float* __restrict__ outF)
{
  constexpr int NT = KF / 32;  // 76
  __shared__ unsigned short Ah[2][128 * 32];
  __shared__ unsigned short Bh[2][320 * 32];

  const int t = threadIdx.x;
  const int lane = t & 63;
  const int w = t >> 6;
  const int wr = w >> 1, wc = w & 1;

  // XCD mapping: 256 bm panels x 2 bn tiles; 32 panels per XCD
  const int lin = blockIdx.x;
  const int xcd = lin & 7;
  const int sub = lin >> 3;           // 0..63
  const long bm = (long)(xcd * 32 + (sub >> 1)) * 128;
  const int bn = (sub & 1) * 320;

  const int lr = lane & 15, kg = lane >> 4;
  const int Rl = lane >> 2, pch = lane & 3;

  // A: 8 windows; wave w stages windows w, w+4
  const int RA1 = w * 16 + Rl, RA2 = (w + 4) * 16 + Rl;
  const int sA1 = (pch - (RA1 >> 1)) & 3, sA2 = (pch - (RA2 >> 1)) & 3;
  const size_t oA1 = (size_t)(bm + RA1) * KF + sA1 * 8;
  const size_t oA2 = (size_t)(bm + RA2) * KF + sA2 * 8;
  // B: 20 windows; wave w stages windows w*5 .. w*5+4
  size_t oB[5];
#pragma unroll
  for (int j = 0; j < 5; ++j) {
    int q = w * 5 + j;
    int R = q * 16 + Rl;
    int s = (pch - (R >> 1)) & 3;
    oB[j] = (size_t)(bn + R) * KF + s * 8;
  }

  auto STAGE = [&](int buf, int kt) {
    gload16(Ag + oA1 + kt, &Ah[buf][w * 512]);
    gload16(Ag + oA2 + kt, &Ah[buf][(w + 4) * 512]);
#pragma unroll
    for (int j = 0; j < 5; ++j)
      gload16(Bg + oB[j] + kt, &Bh[buf][(w * 5 + j) * 512]);
  };

  const f32x4 fzero = {0.f, 0.f, 0.f, 0.f};
  f32x4 acc[4][10];
#pragma unroll
  for (int m = 0; m < 4; ++m)
#pragma unroll
    for (int n = 0; n < 10; ++n) acc[m][n] = fzero;

  STAGE(0, 0);
  int cur = 0;
  for (int it = 0; it < NT; ++it) {
    if (it + 1 < NT) { STAGE(cur ^ 1, (it + 1) * 32); wait_vm<7>(); }
    else wait_vm<0>();
    barrier_raw();

    bf16x8 af[4];
#pragma unroll
    for (int m = 0; m < 4; ++m) {
      int R = wr * 64 + m * 16 + lr;
      af[m] = *(const bf16x8*)&Ah[cur][R * 32 + (((kg + (R >> 1)) & 3) << 3)];
    }
#pragma unroll
    for (int n = 0; n < 10; ++n) {
      int R = wc * 160 + n * 16 + lr;
      bf16x8 bf = *(const bf16x8*)&Bh[cur][R * 32 + (((kg + (R >> 1)) & 3) << 3)];
#pragma unroll
      for (int m = 0; m < 4; ++m)
        acc[m][n] = __builtin_amdgcn_mfma_f32_16x16x32_bf16(af[m], bf, acc[m][n], 0, 0, 0);
    }
    barrier_raw();
    cur ^= 1;
  }

  // epilogue
#pragma unroll
  for (int m = 0; m < 4; ++m) {
#pragma unroll
    for (int n = 0; n < 10; ++n) {
      long gr0 = bm + wr * 64 + m * 16 + kg * 4;
      int gc = bn + wc * 160 + n * 16 + lr;
      if (gc < NOUT) {
#pragma unroll
        for (int r = 0; r < 4; ++r) {
          float o = acc[m][n][r];
          long row = gr0 + r;
          if (gc < 512) outF[row * 512 + gc] = o;
          else outF[(size_t)BATCH * 512 + row * 96 + (gc - 512)] = o;
        }
      }
    }
  }
}

// ---------- theta projection: coeff[M][32] = h3[M][512] * theta_w[32][512]^T, split-bf16 ----------
__global__ __launch_bounds__(256) void coeff_gemm(
    const unsigned short* __restrict__ Agh, const unsigned short* __restrict__ Agl,
    const unsigned short* __restrict__ Bgh, const unsigned short* __restrict__ Bgl,
    float* __restrict__ coeff)
{
  __shared__ unsigned short Ah[128 * 32];
  __shared__ unsigned short Al[128 * 32];
  __shared__ unsigned short Bh[32 * 32];
  __shared__ unsigned short Bl[32 * 32];

  const int t = threadIdx.x;
  const int lane = t & 63;
  const int w = t >> 6;
  const long bm = (long)blockIdx.x * 128;
  const int lr = lane & 15, kg = lane >> 4;

  const f32x4 fzero = {0.f, 0.f, 0.f, 0.f};
  f32x4 acc[2][2];
#pragma unroll
  for (int m = 0; m < 2; ++m)
#pragma unroll
    for (int n = 0; n < 2; ++n) acc[m][n] = fzero;

  for (int kt = 0; kt < 512; kt += 32) {
    __syncthreads();
#pragma unroll
    for (int p = 0; p < 2; ++p) {
      int c = t + 256 * p;
      int row = c >> 2, slot = c & 3;
      int phys = row * 32 + (((slot + (row >> 1)) & 3) << 3);
      size_t go = (size_t)(bm + row) * UNITS + kt + slot * 8;
      *(s16x8*)&Ah[phys] = *(const s16x8*)&Agh[go];
      *(s16x8*)&Al[phys] = *(const s16x8*)&Agl[go];
    }
    if (t < 128) {
      int row = t >> 2, slot = t & 3;
      int phys = row * 32 + (((slot + (row >> 1)) & 3) << 3);
      size_t go = (size_t)row * UNITS + kt + slot * 8;
      *(s16x8*)&Bh[phys] = *(const s16x8*)&Bgh[go];
      *(s16x8*)&Bl[phys] = *(const s16x8*)&Bgl[go];
    }
    __syncthreads();

    bf16x8 bh[2], bl[2];
#pragma unroll
    for (int n = 0; n < 2; ++n) {
      int R = n * 16 + lr;
      int phys = R * 32 + (((kg + (R >> 1)) & 3) << 3);
      bh[n] = *(const bf16x8*)&Bh[phys];
      bl[n] = *(const bf16x8*)&Bl[phys];
    }
#pragma unroll
    for (int m = 0; m < 2; ++m) {
      int R = w * 32 + m * 16 + lr;
      int phys = R * 32 + (((kg + (R >> 1)) & 3) << 3);
      bf16x8 ah = *(const bf16x8*)&Ah[phys];
      bf16x8 al = *(const bf16x8*)&Al[phys];
#pragma unroll
      for (int n = 0; n < 2; ++n) {
        acc[m][n] = __builtin_amdgcn_mfma_f32_16x16x32_bf16(ah, bh[n], acc[m][n], 0, 0, 0);
        acc[m][n] = __builtin_amdgcn_mfma_f32_16x16x32_bf16(ah, bl[n], acc[m][n], 0, 0, 0);
        acc[m][n] = __builtin_amdgcn_mfma_f32_16x16x32_bf16(al, bh[n], acc[m][n], 0, 0, 0);
      }
    }
  }
#pragma unroll
  for (int m = 0; m < 2; ++m)
#pragma unroll
    for (int n = 0; n < 2; ++n) {
      long gr0 = bm + w * 32 + m * 16 + kg * 4;
      int gc = n * 16 + lr;
#pragma unroll
      for (int r = 0; r < 4; ++r)
        coeff[(size_t)(gr0 + r) * 32 + gc] = acc[m][n][r];
    }
}

// ---------- gaussian head: 1 wave/row, 2 rows per 128-thread block ----------
// Packed-e parked in LDS (removes spills). Pass-1 math in f32x2 (v_pk_fma);
// sm from the SAME packed/truncated bits (consistent renorm). Pass-2 float2
// fma + v_cvt_pk_bf16_f32 store. Closed-form softmax max via endpoint
// convexity; hw trans pipe; base-2: exp(0.5*d^2)==2^((d*s)^2).
__global__ __launch_bounds__(128) void gauss_kernel(
    const float* __restrict__ coeff, const float* __restrict__ fn_g,
    const float* __restrict__ fn_b, const float* __restrict__ wn_g,
    const float* __restrict__ wn_b, const float* __restrict__ freqs,
    unsigned short* __restrict__ amps)
{
  __shared__ u32x4 pkL[2][19][64];   // 38,912 B -> 4 blocks/CU (8 waves)
  const int wid = threadIdx.x >> 6;  // 0..1
  const int t = threadIdx.x & 63;
  const int b = blockIdx.x * 2 + wid;
  const float cv = coeff[(size_t)b * 32 + (t & 31)];
  const float L2E = 1.4426950408889634f;

  float c2[8], c3[8];
  float m2 = 0.f, m3 = 0.f;
#pragma unroll
  for (int g = 0; g < 8; ++g) {
    c2[g] = __shfl(cv, 4 * g + 2);
    c3[g] = __shfl(cv, 4 * g + 3);
    m2 += c2[g]; m3 += c3[g];
  }
  m2 *= 0.125f; m3 *= 0.125f;
  float v2 = 0.f, v3 = 0.f;
#pragma unroll
  for (int g = 0; g < 8; ++g) {
    float d2 = c2[g] - m2; v2 += d2 * d2;
    float d3 = c3[g] - m3; v3 += d3 * d3;
  }
  v2 *= 0.125f; v3 *= 0.125f;
  const float r2 = rsqrtf(v2 + 1e-5f), r3 = rsqrtf(v3 + 1e-5f);

  const float S2 = 0.8493218f;  // sqrt(0.5 * log2(e))
  const float fv0 = freqs[0], fvL = freqs[NF - 1];
  f32x2 aa2[4], oo2[4], mx2[4];
#pragma unroll
  for (int g = 0; g < 8; ++g) {
    float z3 = (c3[g] - m3) * r3 * fn_g[g] + fn_b[g];
    float sig = frcp(1.f + fexp2(-z3 * L2E));
    float cfg = frcp(1.f + sig * 608.f);
    float z2 = (c2[g] - m2) * r2 * wn_g[g] + wn_b[g];
    float x = 10.f * z2;
    float enx = fexp2(-fabsf(x) * L2E);
    float sp = (fmaxf(x, 0.f) + 0.6931471805599453f * flog2(1.f + enx)) * 0.1f;
    float iwg = cfg * frcp(fmaxf(sp, 1e-6f));
    float aag = iwg * S2;
    float oog = cfg * iwg * S2;
    float d0 = fmaf(fv0, aag, -oog);
    float dL = fmaf(fvL, aag, -oog);
    aa2[g >> 1][g & 1] = aag;
    oo2[g >> 1][g & 1] = oog;
    mx2[g >> 1][g & 1] = fmaxf(d0 * d0, dL * dL);
  }

  f32x2 sm2[4];
#pragma unroll
  for (int j = 0; j < 4; ++j) sm2[j] = (f32x2){0.f, 0.f};

  // ---- single exponent pass: packed d/arg (v_pk_fma), scalar exp2,
  //      v_perm pack -> LDS; sm from packed/truncated bits ----
#pragma unroll
  for (int i = 0; i < 19; ++i) {
    int f = t + 64 * i;
    float fv = freqs[min(f, NF - 1)];
    f32x2 fv2 = {fv, fv};
    u32x4 pw;
#pragma unroll
    for (int j = 0; j < 4; ++j) {
      f32x2 d2v = fv2 * aa2[j] - oo2[j];
      f32x2 arg = d2v * d2v - mx2[j];
      float e0 = fexp2(arg[0]);
      float e1 = fexp2(arg[1]);
      if (i == 18 && t == 63) { e0 = 0.f; e1 = 0.f; }
      unsigned p = __builtin_amdgcn_perm(__builtin_bit_cast(unsigned, e1),
                                         __builtin_bit_cast(unsigned, e0),
                                         0x07060302u);  // [e1.hi16|e0.hi16]
      pw[j] = p;
      f32x2 e2;
      e2[0] = __builtin_bit_cast(float, p << 16);
      e2[1] = __builtin_bit_cast(float, p & 0xFFFF0000u);
      sm2[j] += e2;
    }
    pkL[wid][i][t] = pw;  // one ds_write_b128
  }

  f32x2 ws2[4], wc2[4];
#pragma unroll
  for (int j = 0; j < 4; ++j) {
    float s0 = sm2[j][0], s1 = sm2[j][1];
#pragma unroll
    for (int m = 32; m >= 1; m >>= 1) {
      s0 += __shfl_xor(s0, m);
      s1 += __shfl_xor(s1, m);
    }
    float inv0 = frcp(s0), inv1 = frcp(s1);
    ws2[j][0] = __shfl(cv, 8 * j + 0) * inv0;
    ws2[j][1] = __shfl(cv, 8 * j + 4) * inv1;
    wc2[j][0] = __shfl(cv, 8 * j + 1) * inv0;
    wc2[j][1] = __shfl(cv, 8 * j + 5) * inv1;
  }

  // ---- accumulate (packed float2 fma) + store via v_cvt_pk_bf16_f32 ----
  size_t base = (size_t)b * KF;
#pragma unroll
  for (int i = 0; i < 19; ++i) {
    u32x4 pw = pkL[wid][i][t];  // one ds_read_b128
    f32x2 as2 = {0.f, 0.f}, ac2 = {0.f, 0.f};
#pragma unroll
    for (int j = 0; j < 4; ++j) {
      f32x2 e2;
      e2[0] = __builtin_bit_cast(float, pw[j] << 16);
      e2[1] = __builtin_bit_cast(float, pw[j] & 0xFFFF0000u);
      as2 += e2 * ws2[j];
      ac2 += e2 * wc2[j];
    }
    float as = as2[0] + as2[1];
    float ac = ac2[0] + ac2[1];
    int f = t + 64 * i;
    if (f < NF) {
      unsigned r;
      asm("v_cvt_pk_bf16_f32 %0, %1, %2" : "=v"(r) : "v"(as), "v"(ac));
      amps[base + f] = (unsigned short)(r & 0xFFFFu);
      amps[base + NF + f] = (unsigned short)(r >> 16);
    }
  }
  if (t == 0) {
    amps[base + 2430] = 0;
    amps[base + 2431] = 0;
  }
}

extern "C" void kernel_launch(void* const* d_in, const int* in_sizes, int n_in,
                              void* d_out, int out_size, void* d_ws, size_t ws_size,
                              hipStream_t stream) {
  (void)in_sizes; (void)n_in; (void)out_size; (void)ws_size;
  const float* x = (const float*)d_in[0];
  const float* fcw[4] = {(const float*)d_in[1], (const float*)d_in[3],
                         (const float*)d_in[5], (const float*)d_in[7]};
  const float* fcb[4] = {(const float*)d_in[2], (const float*)d_in[4],
                         (const float*)d_in[6], (const float*)d_in[8]};
  const float* theta_w = (const float*)d_in[9];
  const float* fn_g = (const float*)d_in[10];
  const float* fn_b = (const float*)d_in[11];
  const float* wn_g = (const float*)d_in[12];
  const float* wn_b = (const float*)d_in[13];
  const float* freqs = (const float*)d_in[14];
  const float* sb = (const float*)d_in[15];
  const float* sf = (const float*)d_in[16];
  float* out = (float*)d_out;

  char* p = (char*)d_ws;
  auto take = [&](size_t bytes) {
    char* r = p;
    p += (bytes + 255) & ~(size_t)255;
    return r;
  };
  unsigned short* h0h = (unsigned short*)take((size_t)BATCH * UNITS * 2);
  unsigned short* h0l = (unsigned short*)take((size_t)BATCH * UNITS * 2);
  unsigned short* h1h = (unsigned short*)take((size_t)BATCH * UNITS * 2);
  unsigned short* h1l = (unsigned short*)take((size_t)BATCH * UNITS * 2);
  unsigned short *wh[4], *wl[4];
  for (int l = 0; l < 4; ++l) {
    wh[l] = (unsigned short*)take((size_t)UNITS * UNITS * 2);
    wl[l] = (unsigned short*)take((size_t)UNITS * UNITS * 2);
  }
  unsigned short* twh = (unsigned short*)take((size_t)32 * UNITS * 2);
  unsigned short* twl = (unsigned short*)take((size_t)32 * UNITS * 2);
  float* coeff = (float*)take((size_t)BATCH * 32 * 4);
  unsigned short* st = (unsigned short*)take((size_t)640 * KF * 2);
  unsigned short* amps = (unsigned short*)take((size_t)BATCH * KF * 2);

  // prep: all fp32->bf16(hi,lo) splits in ONE launch
  SplitArgs sa;
  sa.seg[0] = {x,       h0h,   h0l,   (unsigned)(BATCH * UNITS / 4)};
  sa.seg[1] = {fcw[0],  wh[0], wl[0], (unsigned)(UNITS * UNITS / 4)};
  sa.seg[2] = {fcw[1],  wh[1], wl[1], (unsigned)(UNITS * UNITS / 4)};
  sa.seg[3] = {fcw[2],  wh[2], wl[2], (unsigned)(UNITS * UNITS / 4)};
  sa.seg[4] = {fcw[3],  wh[3], wl[3], (unsigned)(UNITS * UNITS / 4)};
  sa.seg[5] = {theta_w, twh,   twl,   (unsigned)(32 * UNITS / 4)};
  sa.total4 = (unsigned)(BATCH * UNITS / 4 + 4 * (UNITS * UNITS / 4) + 32 * UNITS / 4);
  split_all<<<2048, 256, 0, stream>>>(sa);
  st_prep<<<dim3(KF / 32, 640 / 32), dim3(32, 8), 0, stream>>>(sb, sf, st);

  // FC stack (split-bf16): x->h1->h0->h1->h0   (1-D grid, XCD-aware mapping)
  gemm_fc<4><<<4 * (BATCH / 128), 256, 0, stream>>>(
      h0h, h0l, wh[0], wl[0], fcb[0], h1h, h1l);
  gemm_fc<4><<<4 * (BATCH / 128), 256, 0, stream>>>(
      h1h, h1l, wh[1], wl[1], fcb[1], h0h, h0l);
  gemm_fc<4><<<4 * (BATCH / 128), 256, 0, stream>>>(
      h0h, h0l, wh[2], wl[2], fcb[2], h1h, h1l);
  gemm_fc<4><<<4 * (BATCH / 128), 256, 0, stream>>>(
      h1h, h1l, wh[3], wl[3], fcb[3], h0h, h0l);

  // theta projection
  coeff_gemm<<<BATCH / 128, 256, 0, stream>>>(h0h, h0l, twh, twl, coeff);

  // gaussian head -> amps (bf16, padded to 2432); 1 wave/row, 2 rows/block
  gauss_kernel<<<BATCH / 2, 128, 0, stream>>>(coeff, fn_g, fn_b, wn_g, wn_b, freqs, amps);

  // final GEMM -> backcast + forecast (wide tile: 128x320, 2 bn tiles)
  gemm_wide<<<2 * (BATCH / 128), 256, 0, stream>>>(amps, st, out);
}